// Round 8
// baseline (3347.356 us; speedup 1.0000x reference)
//
#include <hip/hip_runtime.h>

// MyTransformer: 6-enc + 6-dec, S=1024, D=512, H=8x64, FF=2048.
// Round 7: PERSISTENT MEGAKERNEL. One kernel, 240 blocks x 256 thr, all phases
// (QKV / flash-attn / proj / LN / FF1 / FF2 / final LN+L2 / gram) separated by a
// custom two-level grid barrier (device-scope atomics + threadfence). Phase
// bodies are verbatim ports of the round-3/6 kernels (identical math).

#define NLAY 6
#define NB   240
#define NGRP 8
#define GRP  30

typedef __attribute__((ext_vector_type(8))) short short8;
typedef __attribute__((ext_vector_type(4))) short short4v;
typedef __attribute__((ext_vector_type(4))) float f32x4;

typedef __attribute__((address_space(3))) short lds_short;
typedef __attribute__((address_space(1))) const unsigned short g_ushort;

__device__ __forceinline__ void gload16(const unsigned short* g, short* l) {
    __builtin_amdgcn_global_load_lds((g_ushort*)g, (lds_short*)l, 16, 0, 0);
}

__device__ __forceinline__ void waitvm(int n) {
    if (n == 0)      asm volatile("s_waitcnt vmcnt(0)" ::: "memory");
    else if (n == 4) asm volatile("s_waitcnt vmcnt(4)" ::: "memory");
    else if (n == 8) asm volatile("s_waitcnt vmcnt(8)" ::: "memory");
    else             asm volatile("s_waitcnt vmcnt(12)" ::: "memory");
}

__device__ __forceinline__ void waitlgkm0() {
    asm volatile("s_waitcnt lgkmcnt(0)" ::: "memory");
}

__device__ inline unsigned short f2bu(float x) {
    unsigned u = __builtin_bit_cast(unsigned, x);
    unsigned r = (u + 0x7fffu + ((u >> 16) & 1u)) >> 16;   // RNE
    return (unsigned short)r;
}

// ---------------------------- grid barrier -----------------------------------
// bar layout (ints): gen @0; top[s] @16+s*16; cnt[s][g] @64+(s*8+g)*16.
__device__ void gsync(int inst, int* bar) {
    __syncthreads();
    if (threadIdx.x == 0) {
        const int s = inst & 1;
        int* gen = bar;
        int* top = bar + 16 + s * 16;
        int* cnt = bar + 64 + (s * NGRP + (int)(blockIdx.x / GRP)) * 16;
        const int mygen = __hip_atomic_load(gen, __ATOMIC_RELAXED, __HIP_MEMORY_SCOPE_AGENT);
        __threadfence();   // release: flush this block's phase writes
        if (__hip_atomic_fetch_add(cnt, 1, __ATOMIC_ACQ_REL, __HIP_MEMORY_SCOPE_AGENT) == GRP - 1) {
            if (__hip_atomic_fetch_add(top, 1, __ATOMIC_ACQ_REL, __HIP_MEMORY_SCOPE_AGENT) == NGRP - 1) {
                __hip_atomic_store(top, 0, __ATOMIC_RELAXED, __HIP_MEMORY_SCOPE_AGENT);
                #pragma unroll
                for (int g = 0; g < NGRP; ++g)
                    __hip_atomic_store(bar + 64 + (s * NGRP + g) * 16, 0,
                                       __ATOMIC_RELAXED, __HIP_MEMORY_SCOPE_AGENT);
                __hip_atomic_fetch_add(gen, 1, __ATOMIC_RELEASE, __HIP_MEMORY_SCOPE_AGENT);
            }
        }
        int guard = 0;
        while (__hip_atomic_load(gen, __ATOMIC_RELAXED, __HIP_MEMORY_SCOPE_AGENT) == mygen) {
            __builtin_amdgcn_s_sleep(2);
            if (++guard > (1 << 21)) break;   // convert deadlock into fast failure
        }
        __threadfence();   // acquire: invalidate before reading peers' writes
    }
    __syncthreads();
}

// ------ weight GEMM phase: C = A(bf16) @ B(fp32->bf16)^T + bias, 128x64 ------
// LDS: As 3x8192 shorts @UA, Bs 2x4096 shorts @UA+24576 (64 KB).
template<bool RELU, bool OBF16>
__device__ void gemmW_phase(int task, int NT, int MT, short* UA,
    const unsigned short* __restrict__ A,
    const unsigned short* __restrict__ A2, int a2_col, int lda,
    const float* __restrict__ B, int ldb,
    const float* __restrict__ bias,
    void* __restrict__ Cv, int ldc, long sC,
    int K, unsigned short* __restrict__ VTp, int vt_col0, int kz)
{
    short* As = UA;
    short* Bs = UA + 24576;
    __syncthreads();
    const int nx = task % NT;
    const int my = (task / NT) % MT;
    const int bz = task / (NT * MT);
    const int m0 = my * 128;
    const int n0 = nx * 64;
    if (A2 && n0 >= a2_col) A = A2;
    A += (long)bz * kz;
    B += (long)bz * kz;
    const int tid = threadIdx.x;
    const int w  = tid >> 6;
    const int l  = tid & 63;
    const int fr = l & 15;
    const int kc = l >> 4;

    const int brow = tid >> 2;
    const int bk16 = (tid & 3) * 16;
    const int bs0  = (((tid & 3) * 2)     ^ (brow & 7)) * 8;
    const int bs1  = (((tid & 3) * 2 + 1) ^ (brow & 7)) * 8;

    f32x4 acc[2][4] = {};
    const int T = K >> 6;

    auto FILL_A = [&](int t) {
        const int buf = t % 3;
        const int k0 = t * 64;
        #pragma unroll
        for (int it = 0; it < 4; ++it) {
            const int row = w * 32 + it * 8 + (l >> 3);
            const int sl  = ((l & 7) ^ (row & 7)) * 8;
            gload16(A + (long)(m0 + row) * lda + k0 + sl,
                    As + buf * 8192 + (w * 32 + it * 8) * 64);
        }
    };
    auto ISSUE_B = [&](int t, float4 (&br)[4]) {
        const float* src = B + (long)(n0 + brow) * ldb + t * 64 + bk16;
        #pragma unroll
        for (int i = 0; i < 4; ++i) br[i] = *(const float4*)(src + i * 4);
    };
    auto WRITE_B = [&](int t, const float4 (&br)[4]) {
        const int buf = t & 1;
        short8 v0, v1;
        v0[0] = (short)f2bu(br[0].x); v0[1] = (short)f2bu(br[0].y);
        v0[2] = (short)f2bu(br[0].z); v0[3] = (short)f2bu(br[0].w);
        v0[4] = (short)f2bu(br[1].x); v0[5] = (short)f2bu(br[1].y);
        v0[6] = (short)f2bu(br[1].z); v0[7] = (short)f2bu(br[1].w);
        v1[0] = (short)f2bu(br[2].x); v1[1] = (short)f2bu(br[2].y);
        v1[2] = (short)f2bu(br[2].z); v1[3] = (short)f2bu(br[2].w);
        v1[4] = (short)f2bu(br[3].x); v1[5] = (short)f2bu(br[3].y);
        v1[6] = (short)f2bu(br[3].z); v1[7] = (short)f2bu(br[3].w);
        *(short8*)(Bs + buf * 4096 + brow * 64 + bs0) = v0;
        *(short8*)(Bs + buf * 4096 + brow * 64 + bs1) = v1;
    };
    auto COMPUTE = [&](int t) {
        const int ab = t % 3, bb = t & 1;
        #pragma unroll
        for (int ks = 0; ks < 2; ++ks) {
            const int sl = ((ks * 4 + kc) ^ (fr & 7)) * 8;
            short8 af[2], bf[4];
            #pragma unroll
            for (int r = 0; r < 2; ++r)
                af[r] = *(const short8*)(As + ab * 8192 + (w * 32 + r * 16 + fr) * 64 + sl);
            #pragma unroll
            for (int c = 0; c < 4; ++c)
                bf[c] = *(const short8*)(Bs + bb * 4096 + (c * 16 + fr) * 64 + sl);
            #pragma unroll
            for (int r = 0; r < 2; ++r)
                #pragma unroll
                for (int c = 0; c < 4; ++c)
                    acc[r][c] = __builtin_amdgcn_mfma_f32_16x16x32_bf16(af[r], bf[c], acc[r][c], 0, 0, 0);
        }
    };

    float4 br0[4], br1[4];

    FILL_A(0); ISSUE_B(0, br0);
    FILL_A(1); ISSUE_B(1, br1);
    waitvm(8);
    __builtin_amdgcn_sched_barrier(0);
    WRITE_B(0, br0);
    waitlgkm0();
    __builtin_amdgcn_s_barrier();

    for (int t = 0; t < T; ++t) {
        if (t + 2 < T) {
            FILL_A(t + 2);
            if (t & 1) ISSUE_B(t + 2, br1); else ISSUE_B(t + 2, br0);
        }
        COMPUTE(t);
        waitvm((t + 2 < T) ? 8 : 0);
        __builtin_amdgcn_sched_barrier(0);
        if (t + 1 < T) {
            if (t & 1) WRITE_B(t + 1, br0); else WRITE_B(t + 1, br1);
        }
        waitlgkm0();
        __builtin_amdgcn_s_barrier();
    }

    #pragma unroll
    for (int c = 0; c < 4; ++c) {
        const int n = n0 + c * 16 + fr;
        const float bv = bias ? bias[n] : 0.0f;
        const bool do_vt = (VTp != nullptr) && (n >= vt_col0);
        #pragma unroll
        for (int r = 0; r < 2; ++r) {
            #pragma unroll
            for (int i = 0; i < 4; ++i) {
                const long m = m0 + w * 32 + r * 16 + kc * 4 + i;
                float v = acc[r][c][i] + bv;
                if (RELU) v = fmaxf(v, 0.0f);
                if (OBF16) ((unsigned short*)Cv)[bz * sC + m * ldc + n] = f2bu(v);
                else       ((float*)Cv)[bz * sC + m * ldc + n] = v;
                if (do_vt) {
                    const int vc = n - vt_col0;
                    VTp[(long)(vc >> 6) * 65536 + (long)(vc & 63) * 1024 + m] = f2bu(v);
                }
            }
        }
    }
}

// --------------- attention phase: O = softmax(QK^T/8) V (4 waves) ------------
// LDS: Ks 3x4096 @UA, Vs 3x4096 @UA+12288, Ps 4x1024 @UA+24576 (57.3 KB).
__device__ void attn_phase(int task, short* UA,
    const unsigned short* __restrict__ QKVb,
    const unsigned short* __restrict__ VT,
    unsigned short* __restrict__ AOb)
{
    short* Ks = UA;
    short* Vs = UA + 12288;
    short* Ps = UA + 24576;
    __syncthreads();
    const int qt = task & 15;
    const int h  = task >> 4;
    const int tid = threadIdx.x;
    const int w  = tid >> 6;
    const int l  = tid & 63;
    const int fr = l & 15;
    const int kc = l >> 4;

    const int qrow = qt * 64 + w * 16 + fr;
    short8 qf[2];
    qf[0] = *(const short8*)(QKVb + (long)qrow * 1536 + h * 64 + kc * 8);
    qf[1] = *(const short8*)(QKVb + (long)qrow * 1536 + h * 64 + 32 + kc * 8);

    auto FILL = [&](int t, int buf) {
        const int kb = t * 64;
        #pragma unroll
        for (int it = 0; it < 2; ++it) {
            const int row = w * 16 + it * 8 + (l >> 3);
            const int sl  = ((l & 7) ^ (row & 7)) * 8;
            gload16(QKVb + (long)(kb + row) * 1536 + 512 + h * 64 + sl,
                    Ks + buf * 4096 + (w * 16 + it * 8) * 64);
            gload16(VT + (long)h * 65536 + (long)row * 1024 + kb + sl,
                    Vs + buf * 4096 + (w * 16 + it * 8) * 64);
        }
    };

    float m_i[4], l_i[4];
    f32x4 acc_o[4] = {};
    #pragma unroll
    for (int i = 0; i < 4; ++i) { m_i[i] = -1e30f; l_i[i] = 0.f; }

    short* ps = Ps + w * 1024;

    FILL(0, 0); FILL(1, 1);
    int fb = 2, cb = 0;
    for (int t = 0; t < 16; ++t) {
        waitvm(t == 15 ? 0 : 4);
        __builtin_amdgcn_sched_barrier(0);
        __builtin_amdgcn_s_barrier();
        if (t + 2 < 16) { FILL(t + 2, fb); fb = (fb == 2) ? 0 : fb + 1; }

        f32x4 sacc[4] = {};
        #pragma unroll
        for (int ks = 0; ks < 2; ++ks) {
            #pragma unroll
            for (int c = 0; c < 4; ++c) {
                const int krow = c * 16 + fr;
                const short8 kf = *(const short8*)(Ks + cb * 4096 + krow * 64 + (((ks * 4 + kc) ^ (krow & 7)) * 8));
                sacc[c] = __builtin_amdgcn_mfma_f32_16x16x32_bf16(qf[ks], kf, sacc[c], 0, 0, 0);
            }
        }

        float p[4][4];
        #pragma unroll
        for (int i = 0; i < 4; ++i) {
            float tm = fmaxf(fmaxf(sacc[0][i], sacc[1][i]), fmaxf(sacc[2][i], sacc[3][i]));
            #pragma unroll
            for (int off = 8; off; off >>= 1) tm = fmaxf(tm, __shfl_xor(tm, off));
            tm *= 0.125f;
            const float mn = fmaxf(m_i[i], tm);
            const float sc = __expf(m_i[i] - mn);
            m_i[i] = mn;
            float ts = 0.f;
            #pragma unroll
            for (int c = 0; c < 4; ++c) { p[c][i] = __expf(sacc[c][i] * 0.125f - mn); ts += p[c][i]; }
            #pragma unroll
            for (int off = 8; off; off >>= 1) ts += __shfl_xor(ts, off);
            l_i[i] = l_i[i] * sc + ts;
            #pragma unroll
            for (int c = 0; c < 4; ++c) acc_o[c][i] *= sc;
        }

        #pragma unroll
        for (int c = 0; c < 4; ++c) {
            const int col = c * 16 + fr;
            #pragma unroll
            for (int i = 0; i < 4; ++i) {
                const int row = kc * 4 + i;
                ps[row * 64 + (((col >> 3) ^ (row & 7)) * 8) + (col & 7)] = (short)f2bu(p[c][i]);
            }
        }
        short8 pf[2];
        pf[0] = *(const short8*)(ps + fr * 64 + ((kc ^ (fr & 7)) * 8));
        pf[1] = *(const short8*)(ps + fr * 64 + (((4 + kc) ^ (fr & 7)) * 8));

        #pragma unroll
        for (int ks = 0; ks < 2; ++ks) {
            #pragma unroll
            for (int c = 0; c < 4; ++c) {
                const int drow = c * 16 + fr;
                const short8 vf = *(const short8*)(Vs + cb * 4096 + drow * 64 + (((ks * 4 + kc) ^ (drow & 7)) * 8));
                acc_o[c] = __builtin_amdgcn_mfma_f32_16x16x32_bf16(pf[ks], vf, acc_o[c], 0, 0, 0);
            }
        }
        cb = (cb == 2) ? 0 : cb + 1;
    }

    #pragma unroll
    for (int c = 0; c < 4; ++c) {
        const int dcol = h * 64 + c * 16 + fr;
        #pragma unroll
        for (int i = 0; i < 4; ++i) {
            const int row = qt * 64 + w * 16 + kc * 4 + i;
            AOb[(long)row * 512 + dcol] = f2bu(acc_o[c][i] / l_i[i]);
        }
    }
}

// -------- bf16 x bf16 GEMM phase (gram): 64x64 tile, 5-buf pipeline ----------
// LDS: As 5x4096 @UA, Bs 5x4096 @UA+20480 (80 KB).
__device__ void gemmG_phase(int task, short* UA,
    const unsigned short* __restrict__ A, int lda,
    const unsigned short* __restrict__ B, int ldb,
    float* __restrict__ C, int ldc, int K)
{
    short* As = UA;
    short* Bs = UA + 20480;
    __syncthreads();
    const int nx = task & 15;
    const int my = task >> 4;
    const int m0 = my * 64;
    const int n0 = nx * 64;
    const int tid = threadIdx.x;
    const int w  = tid >> 6;
    const int l  = tid & 63;
    const int fr = l & 15;
    const int kc = l >> 4;

    f32x4 acc[4] = {};
    const int T = K >> 6;

    auto FILL = [&](int t, int buf) {
        const int k0 = t * 64;
        #pragma unroll
        for (int it = 0; it < 2; ++it) {
            const int row = w * 16 + it * 8 + (l >> 3);
            const int sl  = ((l & 7) ^ (row & 7)) * 8;
            gload16(A + (long)(m0 + row) * lda + k0 + sl, As + buf * 4096 + (w * 16 + it * 8) * 64);
            gload16(B + (long)(n0 + row) * ldb + k0 + sl, Bs + buf * 4096 + (w * 16 + it * 8) * 64);
        }
    };

    FILL(0, 0);
    if (T > 1) FILL(1, 1);
    if (T > 2) FILL(2, 2);
    if (T > 3) FILL(3, 3);
    int cb = 0, fb = 4;
    for (int t = 0; t < T; ++t) {
        const int rem = T - 1 - t;
        waitvm(rem >= 3 ? 12 : rem * 4);
        __builtin_amdgcn_sched_barrier(0);
        __builtin_amdgcn_s_barrier();
        if (t + 4 < T) FILL(t + 4, fb);
        fb = (fb == 4) ? 0 : fb + 1;
        #pragma unroll
        for (int ks = 0; ks < 2; ++ks) {
            const int arow = w * 16 + fr;
            const short8 af = *(const short8*)(As + cb * 4096 + arow * 64 + (((ks * 4 + kc) ^ (arow & 7)) * 8));
            #pragma unroll
            for (int c = 0; c < 4; ++c) {
                const int brn = c * 16 + fr;
                const short8 bf = *(const short8*)(Bs + cb * 4096 + brn * 64 + (((ks * 4 + kc) ^ (brn & 7)) * 8));
                acc[c] = __builtin_amdgcn_mfma_f32_16x16x32_bf16(af, bf, acc[c], 0, 0, 0);
            }
        }
        cb = (cb == 4) ? 0 : cb + 1;
    }

    #pragma unroll
    for (int c = 0; c < 4; ++c) {
        const int n = n0 + c * 16 + fr;
        #pragma unroll
        for (int i = 0; i < 4; ++i) {
            const long m = m0 + w * 16 + kc * 4 + i;
            C[m * ldc + n] = acc[c][i];
        }
    }
}

// -------- LayerNorm phase: out = LN(x + sum_slabs + bias)*s + b --------------
template<int NSLAB>
__device__ void ln_phase(int task, const float* __restrict__ x,
                         const float* __restrict__ slab, const float* __restrict__ bias,
                         const float* __restrict__ s, const float* __restrict__ bb,
                         float* __restrict__ out, unsigned short* __restrict__ outb)
{
    const int lane = threadIdx.x & 63;
    const int row  = (task << 2) + (threadIdx.x >> 6);
    const float* px = x + (long)row * 512;
    float v[8];
    float sum = 0.f;
    #pragma unroll
    for (int i = 0; i < 8; ++i) {
        const int j = lane + (i << 6);
        v[i] = px[j];
        #pragma unroll
        for (int t = 0; t < NSLAB; ++t) v[i] += slab[(long)t * 524288 + (long)row * 512 + j];
        if (NSLAB > 0) v[i] += bias[j];
        sum += v[i];
    }
    #pragma unroll
    for (int off = 32; off; off >>= 1) sum += __shfl_xor(sum, off);
    const float m = sum * (1.0f / 512.0f);
    float s2 = 0.f;
    #pragma unroll
    for (int i = 0; i < 8; ++i) { const float d = v[i] - m; s2 += d * d; }
    #pragma unroll
    for (int off = 32; off; off >>= 1) s2 += __shfl_xor(s2, off);
    const float inv = rsqrtf(s2 * (1.0f / 512.0f) + 1e-5f);
    #pragma unroll
    for (int i = 0; i < 8; ++i) {
        const int j = lane + (i << 6);
        const float r = (v[i] - m) * inv * s[j] + bb[j];
        out[(long)row * 512 + j] = r;
        outb[(long)row * 512 + j] = f2bu(r);
    }
}

// -------- fused final LN + L2-normalize phase --------------------------------
__device__ void lnl2_phase(int task, const float* __restrict__ x,
                           const float* __restrict__ s, const float* __restrict__ bb,
                           float* __restrict__ out_attn, unsigned short* __restrict__ nb)
{
    const int lane = threadIdx.x & 63;
    const int row  = (task << 2) + (threadIdx.x >> 6);
    const float* px = x + (long)row * 512;
    float v[8];
    float sum = 0.f;
    #pragma unroll
    for (int i = 0; i < 8; ++i) { v[i] = px[lane + (i << 6)]; sum += v[i]; }
    #pragma unroll
    for (int off = 32; off; off >>= 1) sum += __shfl_xor(sum, off);
    const float m = sum * (1.0f / 512.0f);
    float s2 = 0.f;
    #pragma unroll
    for (int i = 0; i < 8; ++i) { const float d = v[i] - m; s2 += d * d; }
    #pragma unroll
    for (int off = 32; off; off >>= 1) s2 += __shfl_xor(s2, off);
    const float inv = rsqrtf(s2 * (1.0f / 512.0f) + 1e-5f);
    float nrm = 0.f;
    #pragma unroll
    for (int i = 0; i < 8; ++i) {
        const int j = lane + (i << 6);
        v[i] = (v[i] - m) * inv * s[j] + bb[j];
        out_attn[(long)row * 512 + j] = v[i];
        nrm += v[i] * v[i];
    }
    #pragma unroll
    for (int off = 32; off; off >>= 1) nrm += __shfl_xor(nrm, off);
    const float rinv = rsqrtf(nrm);
    #pragma unroll
    for (int i = 0; i < 8; ++i)
        nb[(long)row * 512 + lane + (i << 6)] = f2bu(v[i] * rinv);
}

// ------------------------------- params --------------------------------------
struct Params {
    const float *enc_qkv_w, *enc_qkv_b, *enc_out_w, *enc_out_b;
    const float *enc_ff1_w, *enc_ff1_b, *enc_ff2_w, *enc_ff2_b;
    const float *enc_ln1_s, *enc_ln1_b, *enc_ln2_s, *enc_ln2_b;
    const float *dec_sa_qkv_w, *dec_sa_qkv_b, *dec_sa_out_w, *dec_sa_out_b;
    const float *dec_ca_qkv_w, *dec_ca_qkv_b, *dec_ca_out_w, *dec_ca_out_b;
    const float *dec_ff1_w, *dec_ff1_b, *dec_ff2_w, *dec_ff2_b;
    const float *dec_ln1_s, *dec_ln1_b, *dec_ln2_s, *dec_ln2_b, *dec_ln3_s, *dec_ln3_b;
    const float *enc_norm_s, *enc_norm_b, *dec_norm_s, *dec_norm_b;
    float *MEMf, *Yf, *SLAB;
    unsigned short *MEMb, *Yb, *QKVb, *VT, *AOb, *F1b, *NBb;
    float *out_gram, *out_attn;
    int *bar;
};

// ------------------------------ megakernel -----------------------------------
__global__ __launch_bounds__(256)
void mega_k(Params P)
{
    __shared__ __align__(16) short U[40960];   // 80 KB union
    short* UA = U;
    const int b = blockIdx.x;
    int* bar = P.bar;
    int inst = 0;

    // ----------------------------- encoder -----------------------------------
    for (int i = 0; i < NLAY; ++i) {
        for (int t = b; t < 192; t += NB)
            gemmW_phase<false, true>(t, 24, 8, UA, P.MEMb, nullptr, 0, 512,
                P.enc_qkv_w + (long)i * 1536 * 512, 512, P.enc_qkv_b + i * 1536,
                P.QKVb, 1536, 0, 512, P.VT, 1024, 0);
        gsync(inst++, bar);
        for (int t = b; t < 128; t += NB) attn_phase(t, UA, P.QKVb, P.VT, P.AOb);
        gsync(inst++, bar);
        for (int t = b; t < 128; t += NB)
            gemmW_phase<false, false>(t, 8, 8, UA, P.AOb, nullptr, 0, 512,
                P.enc_out_w + (long)i * 512 * 512, 512, nullptr,
                P.SLAB, 512, 524288, 256, nullptr, 0, 256);
        gsync(inst++, bar);
        for (int t = b; t < 256; t += NB)
            ln_phase<2>(t, P.MEMf, P.SLAB, P.enc_out_b + i * 512,
                        P.enc_ln1_s + i * 512, P.enc_ln1_b + i * 512, P.MEMf, P.MEMb);
        gsync(inst++, bar);
        for (int t = b; t < 256; t += NB)
            gemmW_phase<true, true>(t, 32, 8, UA, P.MEMb, nullptr, 0, 512,
                P.enc_ff1_w + (long)i * 2048 * 512, 512, P.enc_ff1_b + i * 2048,
                P.F1b, 2048, 0, 512, nullptr, 0, 0);
        gsync(inst++, bar);
        for (int t = b; t < 256; t += NB)
            gemmW_phase<false, false>(t, 8, 8, UA, P.F1b, nullptr, 0, 2048,
                P.enc_ff2_w + (long)i * 512 * 2048, 2048, nullptr,
                P.SLAB, 512, 524288, 512, nullptr, 0, 512);
        gsync(inst++, bar);
        for (int t = b; t < 256; t += NB)
            ln_phase<4>(t, P.MEMf, P.SLAB, P.enc_ff2_b + i * 512,
                        P.enc_ln2_s + i * 512, P.enc_ln2_b + i * 512, P.MEMf, P.MEMb);
        gsync(inst++, bar);
    }
    for (int t = b; t < 256; t += NB)
        ln_phase<0>(t, P.MEMf, nullptr, nullptr, P.enc_norm_s, P.enc_norm_b, P.MEMf, P.MEMb);
    gsync(inst++, bar);

    // ----------------------------- decoder -----------------------------------
    for (int i = 0; i < NLAY; ++i) {
        // self-attention
        for (int t = b; t < 192; t += NB)
            gemmW_phase<false, true>(t, 24, 8, UA, P.Yb, nullptr, 0, 512,
                P.dec_sa_qkv_w + (long)i * 1536 * 512, 512, P.dec_sa_qkv_b + i * 1536,
                P.QKVb, 1536, 0, 512, P.VT, 1024, 0);
        gsync(inst++, bar);
        for (int t = b; t < 128; t += NB) attn_phase(t, UA, P.QKVb, P.VT, P.AOb);
        gsync(inst++, bar);
        for (int t = b; t < 128; t += NB)
            gemmW_phase<false, false>(t, 8, 8, UA, P.AOb, nullptr, 0, 512,
                P.dec_sa_out_w + (long)i * 512 * 512, 512, nullptr,
                P.SLAB, 512, 524288, 256, nullptr, 0, 256);
        gsync(inst++, bar);
        for (int t = b; t < 256; t += NB)
            ln_phase<2>(t, P.Yf, P.SLAB, P.dec_sa_out_b + i * 512,
                        P.dec_ln1_s + i * 512, P.dec_ln1_b + i * 512, P.Yf, P.Yb);
        gsync(inst++, bar);
        // cross-attention (Q from Yb, K/V from MEMb via A2 column split)
        for (int t = b; t < 192; t += NB)
            gemmW_phase<false, true>(t, 24, 8, UA, P.Yb, P.MEMb, 512, 512,
                P.dec_ca_qkv_w + (long)i * 1536 * 512, 512, P.dec_ca_qkv_b + i * 1536,
                P.QKVb, 1536, 0, 512, P.VT, 1024, 0);
        gsync(inst++, bar);
        for (int t = b; t < 128; t += NB) attn_phase(t, UA, P.QKVb, P.VT, P.AOb);
        gsync(inst++, bar);
        for (int t = b; t < 128; t += NB)
            gemmW_phase<false, false>(t, 8, 8, UA, P.AOb, nullptr, 0, 512,
                P.dec_ca_out_w + (long)i * 512 * 512, 512, nullptr,
                P.SLAB, 512, 524288, 256, nullptr, 0, 256);
        gsync(inst++, bar);
        for (int t = b; t < 256; t += NB)
            ln_phase<2>(t, P.Yf, P.SLAB, P.dec_ca_out_b + i * 512,
                        P.dec_ln2_s + i * 512, P.dec_ln2_b + i * 512, P.Yf, P.Yb);
        gsync(inst++, bar);
        // FFN
        for (int t = b; t < 256; t += NB)
            gemmW_phase<true, true>(t, 32, 8, UA, P.Yb, nullptr, 0, 512,
                P.dec_ff1_w + (long)i * 2048 * 512, 512, P.dec_ff1_b + i * 2048,
                P.F1b, 2048, 0, 512, nullptr, 0, 0);
        gsync(inst++, bar);
        for (int t = b; t < 256; t += NB)
            gemmW_phase<false, false>(t, 8, 8, UA, P.F1b, nullptr, 0, 2048,
                P.dec_ff2_w + (long)i * 512 * 2048, 2048, nullptr,
                P.SLAB, 512, 524288, 512, nullptr, 0, 512);
        gsync(inst++, bar);
        for (int t = b; t < 256; t += NB)
            ln_phase<4>(t, P.Yf, P.SLAB, P.dec_ff2_b + i * 512,
                        P.dec_ln3_s + i * 512, P.dec_ln3_b + i * 512, P.Yf, P.Yb);
        gsync(inst++, bar);
    }

    // ------------------------------ final ------------------------------------
    for (int t = b; t < 256; t += NB)
        lnl2_phase(t, P.Yf, P.dec_norm_s, P.dec_norm_b, P.out_attn, P.NBb);
    gsync(inst++, bar);
    for (int t = b; t < 256; t += NB)
        gemmG_phase(t, UA, P.NBb, 512, P.NBb, 512, P.out_gram, 1024, 512);
}

// -------- init: zero barrier + x -> MEMf, Yf (fp32) + MEMb, Yb (bf16) --------
__global__ __launch_bounds__(256)
void init_k(const float* __restrict__ x, float* __restrict__ mf, float* __restrict__ yf,
            unsigned short* __restrict__ mb, unsigned short* __restrict__ yb,
            int* __restrict__ bar)
{
    if (blockIdx.x == 0) {
        for (int i = threadIdx.x; i < 1024; i += 256) bar[i] = 0;
    }
    const long i = ((long)blockIdx.x * 256 + threadIdx.x) * 4;
    const float4 v = *(const float4*)(x + i);
    *(float4*)(mf + i) = v;
    *(float4*)(yf + i) = v;
    short4v s;
    s[0] = (short)f2bu(v.x); s[1] = (short)f2bu(v.y);
    s[2] = (short)f2bu(v.z); s[3] = (short)f2bu(v.w);
    *(short4v*)(mb + i) = s;
    *(short4v*)(yb + i) = s;
}

// ------------------------------ host side ------------------------------------
extern "C" void kernel_launch(void* const* d_in, const int* in_sizes, int n_in,
                              void* d_out, int out_size, void* d_ws, size_t ws_size,
                              hipStream_t stream)
{
    char* p = (char*)d_ws;
    auto alloc = [&](size_t bytes) -> char* {
        char* r = p; p += (bytes + 255) & ~(size_t)255; return r;
    };
    int*            BAR  = (int*)alloc(4096);
    float*          MEMf = (float*)alloc(1024 * 512 * 4);
    float*          Yf   = (float*)alloc(1024 * 512 * 4);
    unsigned short* MEMb = (unsigned short*)alloc(1024 * 512 * 2);
    unsigned short* Yb   = (unsigned short*)alloc(1024 * 512 * 2);
    unsigned short* QKVb = (unsigned short*)alloc(1024 * 1536 * 2);
    unsigned short* VT   = (unsigned short*)alloc(8L * 64 * 1024 * 2);
    unsigned short* AOb  = (unsigned short*)alloc(1024 * 512 * 2);
    float*          SLAB = (float*)alloc(4L * 1024 * 512 * 4);
    unsigned short* F1b  = (unsigned short*)alloc(1024L * 2048 * 2);
    unsigned short* NBb  = (unsigned short*)alloc(1024 * 512 * 2);

    Params P;
    P.enc_qkv_w    = (const float*)d_in[1];  P.enc_qkv_b    = (const float*)d_in[2];
    P.enc_out_w    = (const float*)d_in[3];  P.enc_out_b    = (const float*)d_in[4];
    P.enc_ff1_w    = (const float*)d_in[5];  P.enc_ff1_b    = (const float*)d_in[6];
    P.enc_ff2_w    = (const float*)d_in[7];  P.enc_ff2_b    = (const float*)d_in[8];
    P.enc_ln1_s    = (const float*)d_in[9];  P.enc_ln1_b    = (const float*)d_in[10];
    P.enc_ln2_s    = (const float*)d_in[11]; P.enc_ln2_b    = (const float*)d_in[12];
    P.dec_sa_qkv_w = (const float*)d_in[13]; P.dec_sa_qkv_b = (const float*)d_in[14];
    P.dec_sa_out_w = (const float*)d_in[15]; P.dec_sa_out_b = (const float*)d_in[16];
    P.dec_ca_qkv_w = (const float*)d_in[17]; P.dec_ca_qkv_b = (const float*)d_in[18];
    P.dec_ca_out_w = (const float*)d_in[19]; P.dec_ca_out_b = (const float*)d_in[20];
    P.dec_ff1_w    = (const float*)d_in[21]; P.dec_ff1_b    = (const float*)d_in[22];
    P.dec_ff2_w    = (const float*)d_in[23]; P.dec_ff2_b    = (const float*)d_in[24];
    P.dec_ln1_s    = (const float*)d_in[25]; P.dec_ln1_b    = (const float*)d_in[26];
    P.dec_ln2_s    = (const float*)d_in[27]; P.dec_ln2_b    = (const float*)d_in[28];
    P.dec_ln3_s    = (const float*)d_in[29]; P.dec_ln3_b    = (const float*)d_in[30];
    P.enc_norm_s   = (const float*)d_in[31]; P.enc_norm_b   = (const float*)d_in[32];
    P.dec_norm_s   = (const float*)d_in[33]; P.dec_norm_b   = (const float*)d_in[34];
    P.MEMf = MEMf; P.Yf = Yf; P.SLAB = SLAB;
    P.MEMb = MEMb; P.Yb = Yb; P.QKVb = QKVb; P.VT = VT; P.AOb = AOb;
    P.F1b = F1b;   P.NBb = NBb;
    P.out_gram = (float*)d_out;
    P.out_attn = P.out_gram + 1024 * 1024;
    P.bar = BAR;

    init_k<<<512, 256, 0, stream>>>((const float*)d_in[0], MEMf, Yf, MEMb, Yb, BAR);
    mega_k<<<NB, 256, 0, stream>>>(P);
}

// Round 9
// 3347.005 us; speedup vs baseline: 1.0001x; 1.0001x over previous
//
#include <hip/hip_runtime.h>

// MyTransformer: 6-enc + 6-dec, S=1024, D=512, H=8x64, FF=2048.
// Round 8: megakernel v2 — 56 KB LDS union (2 blocks/CU), NB via occupancy
// query (512 => 8 waves/CU), wrap-free task counts (all GEMMs 64x64 tiles,
// FF2 split-K x4, proj split-K x2). Phase math identical to rounds 5-7.

#define NLAY 6

typedef __attribute__((ext_vector_type(8))) short short8;
typedef __attribute__((ext_vector_type(4))) short short4v;
typedef __attribute__((ext_vector_type(4))) float f32x4;

typedef __attribute__((address_space(3))) short lds_short;
typedef __attribute__((address_space(1))) const unsigned short g_ushort;

__device__ __forceinline__ void gload16(const unsigned short* g, short* l) {
    __builtin_amdgcn_global_load_lds((g_ushort*)g, (lds_short*)l, 16, 0, 0);
}

__device__ __forceinline__ void waitvm(int n) {
    if (n == 0)      asm volatile("s_waitcnt vmcnt(0)" ::: "memory");
    else if (n == 4) asm volatile("s_waitcnt vmcnt(4)" ::: "memory");
    else             asm volatile("s_waitcnt vmcnt(8)" ::: "memory");
}

__device__ __forceinline__ void waitlgkm0() {
    asm volatile("s_waitcnt lgkmcnt(0)" ::: "memory");
}

__device__ inline unsigned short f2bu(float x) {
    unsigned u = __builtin_bit_cast(unsigned, x);
    unsigned r = (u + 0x7fffu + ((u >> 16) & 1u)) >> 16;   // RNE
    return (unsigned short)r;
}

// ---------------------------- grid barrier -----------------------------------
// bar ints: gen @0; top[s] @16+s*16; cnt[s][g] @64+(s*16+g)*16. GRP=32 blocks.
__device__ void gsync(int inst, int* bar, int ngrp) {
    __syncthreads();
    if (threadIdx.x == 0) {
        const int s = inst & 1;
        int* gen = bar;
        int* top = bar + 16 + s * 16;
        int* cnt = bar + 64 + (s * 16 + (int)(blockIdx.x >> 5)) * 16;
        const int mygen = __hip_atomic_load(gen, __ATOMIC_RELAXED, __HIP_MEMORY_SCOPE_AGENT);
        __threadfence();   // release
        if (__hip_atomic_fetch_add(cnt, 1, __ATOMIC_ACQ_REL, __HIP_MEMORY_SCOPE_AGENT) == 31) {
            if (__hip_atomic_fetch_add(top, 1, __ATOMIC_ACQ_REL, __HIP_MEMORY_SCOPE_AGENT) == ngrp - 1) {
                __hip_atomic_store(top, 0, __ATOMIC_RELAXED, __HIP_MEMORY_SCOPE_AGENT);
                for (int g = 0; g < ngrp; ++g)
                    __hip_atomic_store(bar + 64 + (s * 16 + g) * 16, 0,
                                       __ATOMIC_RELAXED, __HIP_MEMORY_SCOPE_AGENT);
                __hip_atomic_fetch_add(gen, 1, __ATOMIC_RELEASE, __HIP_MEMORY_SCOPE_AGENT);
            }
        }
        int guard = 0;
        while (__hip_atomic_load(gen, __ATOMIC_RELAXED, __HIP_MEMORY_SCOPE_AGENT) == mygen) {
            __builtin_amdgcn_s_sleep(2);
            if (++guard > (1 << 21)) break;
        }
        __threadfence();   // acquire
    }
    __syncthreads();
}

// ------ weight GEMM phase: C = A(bf16) @ B(fp32->bf16)^T + bias, 64x64 -------
// LDS: As 3x4096 @UA (24KB), Bs 2x4096 @UA+12288 (16KB). Wave w: rows w*16..+16.
template<bool RELU, bool OBF16>
__device__ void gemmW_phase(int task, int NT, int MT, short* UA,
    const unsigned short* __restrict__ A,
    const unsigned short* __restrict__ A2, int a2_col, int lda,
    const float* __restrict__ B, int ldb,
    const float* __restrict__ bias,
    void* __restrict__ Cv, int ldc, long sC,
    int K, unsigned short* __restrict__ VTp, int vt_col0, int kz)
{
    short* As = UA;
    short* Bs = UA + 12288;
    __syncthreads();
    const int nx = task % NT;
    const int my = (task / NT) % MT;
    const int bz = task / (NT * MT);
    const int m0 = my * 64;
    const int n0 = nx * 64;
    if (A2 && n0 >= a2_col) A = A2;
    A += (long)bz * kz;
    B += (long)bz * kz;
    const int tid = threadIdx.x;
    const int w  = tid >> 6;
    const int l  = tid & 63;
    const int fr = l & 15;
    const int kc = l >> 4;

    const int brow = tid >> 2;              // 0..63
    const int bk16 = (tid & 3) * 16;
    const int bs0  = (((tid & 3) * 2)     ^ (brow & 7)) * 8;
    const int bs1  = (((tid & 3) * 2 + 1) ^ (brow & 7)) * 8;

    f32x4 acc[4] = {};
    const int T = K >> 6;

    auto FILL_A = [&](int t) {
        const int buf = t % 3;
        const int k0 = t * 64;
        #pragma unroll
        for (int it = 0; it < 2; ++it) {
            const int row = w * 16 + it * 8 + (l >> 3);
            const int sl  = ((l & 7) ^ (row & 7)) * 8;
            gload16(A + (long)(m0 + row) * lda + k0 + sl,
                    As + buf * 4096 + (w * 16 + it * 8) * 64);
        }
    };
    auto ISSUE_B = [&](int t, float4 (&br)[4]) {
        const float* src = B + (long)(n0 + brow) * ldb + t * 64 + bk16;
        #pragma unroll
        for (int i = 0; i < 4; ++i) br[i] = *(const float4*)(src + i * 4);
    };
    auto WRITE_B = [&](int t, const float4 (&br)[4]) {
        const int buf = t & 1;
        short8 v0, v1;
        v0[0] = (short)f2bu(br[0].x); v0[1] = (short)f2bu(br[0].y);
        v0[2] = (short)f2bu(br[0].z); v0[3] = (short)f2bu(br[0].w);
        v0[4] = (short)f2bu(br[1].x); v0[5] = (short)f2bu(br[1].y);
        v0[6] = (short)f2bu(br[1].z); v0[7] = (short)f2bu(br[1].w);
        v1[0] = (short)f2bu(br[2].x); v1[1] = (short)f2bu(br[2].y);
        v1[2] = (short)f2bu(br[2].z); v1[3] = (short)f2bu(br[2].w);
        v1[4] = (short)f2bu(br[3].x); v1[5] = (short)f2bu(br[3].y);
        v1[6] = (short)f2bu(br[3].z); v1[7] = (short)f2bu(br[3].w);
        *(short8*)(Bs + buf * 4096 + brow * 64 + bs0) = v0;
        *(short8*)(Bs + buf * 4096 + brow * 64 + bs1) = v1;
    };
    auto COMPUTE = [&](int t) {
        const int ab = t % 3, bb = t & 1;
        #pragma unroll
        for (int ks = 0; ks < 2; ++ks) {
            const int sl = ((ks * 4 + kc) ^ (fr & 7)) * 8;
            const short8 af = *(const short8*)(As + ab * 4096 + (w * 16 + fr) * 64 + sl);
            #pragma unroll
            for (int c = 0; c < 4; ++c) {
                const short8 bf = *(const short8*)(Bs + bb * 4096 + (c * 16 + fr) * 64 + sl);
                acc[c] = __builtin_amdgcn_mfma_f32_16x16x32_bf16(af, bf, acc[c], 0, 0, 0);
            }
        }
    };

    float4 br0[4], br1[4];

    FILL_A(0); ISSUE_B(0, br0);
    FILL_A(1); ISSUE_B(1, br1);
    waitvm(8);
    __builtin_amdgcn_sched_barrier(0);
    WRITE_B(0, br0);
    waitlgkm0();
    __builtin_amdgcn_s_barrier();

    for (int t = 0; t < T; ++t) {
        if (t + 2 < T) {
            FILL_A(t + 2);
            if (t & 1) ISSUE_B(t + 2, br1); else ISSUE_B(t + 2, br0);
        }
        COMPUTE(t);
        waitvm((t + 2 < T) ? 8 : 0);
        __builtin_amdgcn_sched_barrier(0);
        if (t + 1 < T) {
            if (t & 1) WRITE_B(t + 1, br0); else WRITE_B(t + 1, br1);
        }
        waitlgkm0();
        __builtin_amdgcn_s_barrier();
    }

    #pragma unroll
    for (int c = 0; c < 4; ++c) {
        const int n = n0 + c * 16 + fr;
        const float bv = bias ? bias[n] : 0.0f;
        const bool do_vt = (VTp != nullptr) && (n >= vt_col0);
        #pragma unroll
        for (int i = 0; i < 4; ++i) {
            const long m = m0 + w * 16 + kc * 4 + i;
            float v = acc[c][i] + bv;
            if (RELU) v = fmaxf(v, 0.0f);
            if (OBF16) ((unsigned short*)Cv)[bz * sC + m * ldc + n] = f2bu(v);
            else       ((float*)Cv)[bz * sC + m * ldc + n] = v;
            if (do_vt) {
                const int vc = n - vt_col0;
                VTp[(long)(vc >> 6) * 65536 + (long)(vc & 63) * 1024 + m] = f2bu(v);
            }
        }
    }
}

// --------------- attention phase: O = softmax(QK^T/8) V (4 waves) ------------
// LDS: Ks 3x4096 @UA, Vs 3x4096 @UA+12288, Ps 4x1024 @UA+24576 (56 KB).
__device__ void attn_phase(int task, short* UA,
    const unsigned short* __restrict__ QKVb,
    const unsigned short* __restrict__ VT,
    unsigned short* __restrict__ AOb)
{
    short* Ks = UA;
    short* Vs = UA + 12288;
    short* Ps = UA + 24576;
    __syncthreads();
    const int qt = task & 15;
    const int h  = task >> 4;
    const int tid = threadIdx.x;
    const int w  = tid >> 6;
    const int l  = tid & 63;
    const int fr = l & 15;
    const int kc = l >> 4;

    const int qrow = qt * 64 + w * 16 + fr;
    short8 qf[2];
    qf[0] = *(const short8*)(QKVb + (long)qrow * 1536 + h * 64 + kc * 8);
    qf[1] = *(const short8*)(QKVb + (long)qrow * 1536 + h * 64 + 32 + kc * 8);

    auto FILL = [&](int t, int buf) {
        const int kb = t * 64;
        #pragma unroll
        for (int it = 0; it < 2; ++it) {
            const int row = w * 16 + it * 8 + (l >> 3);
            const int sl  = ((l & 7) ^ (row & 7)) * 8;
            gload16(QKVb + (long)(kb + row) * 1536 + 512 + h * 64 + sl,
                    Ks + buf * 4096 + (w * 16 + it * 8) * 64);
            gload16(VT + (long)h * 65536 + (long)row * 1024 + kb + sl,
                    Vs + buf * 4096 + (w * 16 + it * 8) * 64);
        }
    };

    float m_i[4], l_i[4];
    f32x4 acc_o[4] = {};
    #pragma unroll
    for (int i = 0; i < 4; ++i) { m_i[i] = -1e30f; l_i[i] = 0.f; }

    short* ps = Ps + w * 1024;

    FILL(0, 0); FILL(1, 1);
    int fb = 2, cb = 0;
    for (int t = 0; t < 16; ++t) {
        waitvm(t == 15 ? 0 : 4);
        __builtin_amdgcn_sched_barrier(0);
        __builtin_amdgcn_s_barrier();
        if (t + 2 < 16) { FILL(t + 2, fb); fb = (fb == 2) ? 0 : fb + 1; }

        f32x4 sacc[4] = {};
        #pragma unroll
        for (int ks = 0; ks < 2; ++ks) {
            #pragma unroll
            for (int c = 0; c < 4; ++c) {
                const int krow = c * 16 + fr;
                const short8 kf = *(const short8*)(Ks + cb * 4096 + krow * 64 + (((ks * 4 + kc) ^ (krow & 7)) * 8));
                sacc[c] = __builtin_amdgcn_mfma_f32_16x16x32_bf16(qf[ks], kf, sacc[c], 0, 0, 0);
            }
        }

        float p[4][4];
        #pragma unroll
        for (int i = 0; i < 4; ++i) {
            float tm = fmaxf(fmaxf(sacc[0][i], sacc[1][i]), fmaxf(sacc[2][i], sacc[3][i]));
            #pragma unroll
            for (int off = 8; off; off >>= 1) tm = fmaxf(tm, __shfl_xor(tm, off));
            tm *= 0.125f;
            const float mn = fmaxf(m_i[i], tm);
            const float sc = __expf(m_i[i] - mn);
            m_i[i] = mn;
            float ts = 0.f;
            #pragma unroll
            for (int c = 0; c < 4; ++c) { p[c][i] = __expf(sacc[c][i] * 0.125f - mn); ts += p[c][i]; }
            #pragma unroll
            for (int off = 8; off; off >>= 1) ts += __shfl_xor(ts, off);
            l_i[i] = l_i[i] * sc + ts;
            #pragma unroll
            for (int c = 0; c < 4; ++c) acc_o[c][i] *= sc;
        }

        #pragma unroll
        for (int c = 0; c < 4; ++c) {
            const int col = c * 16 + fr;
            #pragma unroll
            for (int i = 0; i < 4; ++i) {
                const int row = kc * 4 + i;
                ps[row * 64 + (((col >> 3) ^ (row & 7)) * 8) + (col & 7)] = (short)f2bu(p[c][i]);
            }
        }
        short8 pf[2];
        pf[0] = *(const short8*)(ps + fr * 64 + ((kc ^ (fr & 7)) * 8));
        pf[1] = *(const short8*)(ps + fr * 64 + (((4 + kc) ^ (fr & 7)) * 8));

        #pragma unroll
        for (int ks = 0; ks < 2; ++ks) {
            #pragma unroll
            for (int c = 0; c < 4; ++c) {
                const int drow = c * 16 + fr;
                const short8 vf = *(const short8*)(Vs + cb * 4096 + drow * 64 + (((ks * 4 + kc) ^ (drow & 7)) * 8));
                acc_o[c] = __builtin_amdgcn_mfma_f32_16x16x32_bf16(pf[ks], vf, acc_o[c], 0, 0, 0);
            }
        }
        cb = (cb == 2) ? 0 : cb + 1;
    }

    #pragma unroll
    for (int c = 0; c < 4; ++c) {
        const int dcol = h * 64 + c * 16 + fr;
        #pragma unroll
        for (int i = 0; i < 4; ++i) {
            const int row = qt * 64 + w * 16 + kc * 4 + i;
            AOb[(long)row * 512 + dcol] = f2bu(acc_o[c][i] / l_i[i]);
        }
    }
}

// -------- bf16 x bf16 GEMM phase (gram): 64x64 tile, 3-buf pipeline ----------
// LDS: As 3x4096 @UA, Bs 3x4096 @UA+12288 (48 KB).
__device__ void gemmG_phase(int task, short* UA,
    const unsigned short* __restrict__ A, int lda,
    const unsigned short* __restrict__ B, int ldb,
    float* __restrict__ C, int ldc, int K)
{
    short* As = UA;
    short* Bs = UA + 12288;
    __syncthreads();
    const int nx = task & 15;
    const int my = task >> 4;
    const int m0 = my * 64;
    const int n0 = nx * 64;
    const int tid = threadIdx.x;
    const int w  = tid >> 6;
    const int l  = tid & 63;
    const int fr = l & 15;
    const int kc = l >> 4;

    f32x4 acc[4] = {};
    const int T = K >> 6;

    auto FILL = [&](int t) {
        const int buf = t % 3;
        const int k0 = t * 64;
        #pragma unroll
        for (int it = 0; it < 2; ++it) {
            const int row = w * 16 + it * 8 + (l >> 3);
            const int sl  = ((l & 7) ^ (row & 7)) * 8;
            gload16(A + (long)(m0 + row) * lda + k0 + sl, As + buf * 4096 + (w * 16 + it * 8) * 64);
            gload16(B + (long)(n0 + row) * ldb + k0 + sl, Bs + buf * 4096 + (w * 16 + it * 8) * 64);
        }
    };

    FILL(0);
    if (T > 1) FILL(1);
    for (int t = 0; t < T; ++t) {
        waitvm((t + 1 < T) ? 4 : 0);
        __builtin_amdgcn_sched_barrier(0);
        __builtin_amdgcn_s_barrier();
        if (t + 2 < T) FILL(t + 2);
        const int cb = t % 3;
        #pragma unroll
        for (int ks = 0; ks < 2; ++ks) {
            const int arow = w * 16 + fr;
            const short8 af = *(const short8*)(As + cb * 4096 + arow * 64 + (((ks * 4 + kc) ^ (arow & 7)) * 8));
            #pragma unroll
            for (int c = 0; c < 4; ++c) {
                const int brn = c * 16 + fr;
                const short8 bf = *(const short8*)(Bs + cb * 4096 + brn * 64 + (((ks * 4 + kc) ^ (brn & 7)) * 8));
                acc[c] = __builtin_amdgcn_mfma_f32_16x16x32_bf16(af, bf, acc[c], 0, 0, 0);
            }
        }
    }

    #pragma unroll
    for (int c = 0; c < 4; ++c) {
        const int n = n0 + c * 16 + fr;
        #pragma unroll
        for (int i = 0; i < 4; ++i) {
            const long m = m0 + w * 16 + kc * 4 + i;
            C[m * ldc + n] = acc[c][i];
        }
    }
}

// -------- LayerNorm phase: out = LN(x + sum_slabs + bias)*s + b --------------
template<int NSLAB>
__device__ void ln_phase(int task, const float* __restrict__ x,
                         const float* __restrict__ slab, const float* __restrict__ bias,
                         const float* __restrict__ s, const float* __restrict__ bb,
                         float* __restrict__ out, unsigned short* __restrict__ outb)
{
    const int lane = threadIdx.x & 63;
    const int row  = (task << 2) + (threadIdx.x >> 6);
    const float* px = x + (long)row * 512;
    float v[8];
    float sum = 0.f;
    #pragma unroll
    for (int i = 0; i < 8; ++i) {
        const int j = lane + (i << 6);
        v[i] = px[j];
        #pragma unroll
        for (int t = 0; t < NSLAB; ++t) v[i] += slab[(long)t * 524288 + (long)row * 512 + j];
        if (NSLAB > 0) v[i] += bias[j];
        sum += v[i];
    }
    #pragma unroll
    for (int off = 32; off; off >>= 1) sum += __shfl_xor(sum, off);
    const float m = sum * (1.0f / 512.0f);
    float s2 = 0.f;
    #pragma unroll
    for (int i = 0; i < 8; ++i) { const float d = v[i] - m; s2 += d * d; }
    #pragma unroll
    for (int off = 32; off; off >>= 1) s2 += __shfl_xor(s2, off);
    const float inv = rsqrtf(s2 * (1.0f / 512.0f) + 1e-5f);
    #pragma unroll
    for (int i = 0; i < 8; ++i) {
        const int j = lane + (i << 6);
        const float r = (v[i] - m) * inv * s[j] + bb[j];
        out[(long)row * 512 + j] = r;
        outb[(long)row * 512 + j] = f2bu(r);
    }
}

// -------- fused final LN + L2-normalize phase --------------------------------
__device__ void lnl2_phase(int task, const float* __restrict__ x,
                           const float* __restrict__ s, const float* __restrict__ bb,
                           float* __restrict__ out_attn, unsigned short* __restrict__ nb)
{
    const int lane = threadIdx.x & 63;
    const int row  = (task << 2) + (threadIdx.x >> 6);
    const float* px = x + (long)row * 512;
    float v[8];
    float sum = 0.f;
    #pragma unroll
    for (int i = 0; i < 8; ++i) { v[i] = px[lane + (i << 6)]; sum += v[i]; }
    #pragma unroll
    for (int off = 32; off; off >>= 1) sum += __shfl_xor(sum, off);
    const float m = sum * (1.0f / 512.0f);
    float s2 = 0.f;
    #pragma unroll
    for (int i = 0; i < 8; ++i) { const float d = v[i] - m; s2 += d * d; }
    #pragma unroll
    for (int off = 32; off; off >>= 1) s2 += __shfl_xor(s2, off);
    const float inv = rsqrtf(s2 * (1.0f / 512.0f) + 1e-5f);
    float nrm = 0.f;
    #pragma unroll
    for (int i = 0; i < 8; ++i) {
        const int j = lane + (i << 6);
        v[i] = (v[i] - m) * inv * s[j] + bb[j];
        out_attn[(long)row * 512 + j] = v[i];
        nrm += v[i] * v[i];
    }
    #pragma unroll
    for (int off = 32; off; off >>= 1) nrm += __shfl_xor(nrm, off);
    const float rinv = rsqrtf(nrm);
    #pragma unroll
    for (int i = 0; i < 8; ++i)
        nb[(long)row * 512 + lane + (i << 6)] = f2bu(v[i] * rinv);
}

// ------------------------------- params --------------------------------------
struct Params {
    const float *enc_qkv_w, *enc_qkv_b, *enc_out_w, *enc_out_b;
    const float *enc_ff1_w, *enc_ff1_b, *enc_ff2_w, *enc_ff2_b;
    const float *enc_ln1_s, *enc_ln1_b, *enc_ln2_s, *enc_ln2_b;
    const float *dec_sa_qkv_w, *dec_sa_qkv_b, *dec_sa_out_w, *dec_sa_out_b;
    const float *dec_ca_qkv_w, *dec_ca_qkv_b, *dec_ca_out_w, *dec_ca_out_b;
    const float *dec_ff1_w, *dec_ff1_b, *dec_ff2_w, *dec_ff2_b;
    const float *dec_ln1_s, *dec_ln1_b, *dec_ln2_s, *dec_ln2_b, *dec_ln3_s, *dec_ln3_b;
    const float *enc_norm_s, *enc_norm_b, *dec_norm_s, *dec_norm_b;
    float *MEMf, *Yf, *SLAB;
    unsigned short *MEMb, *Yb, *QKVb, *VT, *AOb, *F1b, *NBb;
    float *out_gram, *out_attn;
    int *bar;
    int nb, ngrp;
};

// ------------------------------ megakernel -----------------------------------
__global__ __launch_bounds__(256)
void mega_k(Params P)
{
    __shared__ __align__(16) short U[28672];   // 56 KB union -> 2 blocks/CU
    short* UA = U;
    const int b = blockIdx.x;
    const int nb = P.nb, ngrp = P.ngrp;
    int* bar = P.bar;
    int inst = 0;

    // ----------------------------- encoder -----------------------------------
    for (int i = 0; i < NLAY; ++i) {
        for (int t = b; t < 384; t += nb)
            gemmW_phase<false, true>(t, 24, 16, UA, P.MEMb, nullptr, 0, 512,
                P.enc_qkv_w + (long)i * 1536 * 512, 512, P.enc_qkv_b + i * 1536,
                P.QKVb, 1536, 0, 512, P.VT, 1024, 0);
        gsync(inst++, bar, ngrp);
        for (int t = b; t < 128; t += nb) attn_phase(t, UA, P.QKVb, P.VT, P.AOb);
        gsync(inst++, bar, ngrp);
        for (int t = b; t < 256; t += nb)
            gemmW_phase<false, false>(t, 8, 16, UA, P.AOb, nullptr, 0, 512,
                P.enc_out_w + (long)i * 512 * 512, 512, nullptr,
                P.SLAB, 512, 524288, 256, nullptr, 0, 256);
        gsync(inst++, bar, ngrp);
        for (int t = b; t < 256; t += nb)
            ln_phase<2>(t, P.MEMf, P.SLAB, P.enc_out_b + i * 512,
                        P.enc_ln1_s + i * 512, P.enc_ln1_b + i * 512, P.MEMf, P.MEMb);
        gsync(inst++, bar, ngrp);
        for (int t = b; t < 512; t += nb)
            gemmW_phase<true, true>(t, 32, 16, UA, P.MEMb, nullptr, 0, 512,
                P.enc_ff1_w + (long)i * 2048 * 512, 512, P.enc_ff1_b + i * 2048,
                P.F1b, 2048, 0, 512, nullptr, 0, 0);
        gsync(inst++, bar, ngrp);
        for (int t = b; t < 512; t += nb)
            gemmW_phase<false, false>(t, 8, 16, UA, P.F1b, nullptr, 0, 2048,
                P.enc_ff2_w + (long)i * 512 * 2048, 2048, nullptr,
                P.SLAB, 512, 524288, 512, nullptr, 0, 512);
        gsync(inst++, bar, ngrp);
        for (int t = b; t < 256; t += nb)
            ln_phase<4>(t, P.MEMf, P.SLAB, P.enc_ff2_b + i * 512,
                        P.enc_ln2_s + i * 512, P.enc_ln2_b + i * 512, P.MEMf, P.MEMb);
        gsync(inst++, bar, ngrp);
    }
    for (int t = b; t < 256; t += nb)
        ln_phase<0>(t, P.MEMf, nullptr, nullptr, P.enc_norm_s, P.enc_norm_b, P.MEMf, P.MEMb);
    gsync(inst++, bar, ngrp);

    // ----------------------------- decoder -----------------------------------
    for (int i = 0; i < NLAY; ++i) {
        for (int t = b; t < 384; t += nb)
            gemmW_phase<false, true>(t, 24, 16, UA, P.Yb, nullptr, 0, 512,
                P.dec_sa_qkv_w + (long)i * 1536 * 512, 512, P.dec_sa_qkv_b + i * 1536,
                P.QKVb, 1536, 0, 512, P.VT, 1024, 0);
        gsync(inst++, bar, ngrp);
        for (int t = b; t < 128; t += nb) attn_phase(t, UA, P.QKVb, P.VT, P.AOb);
        gsync(inst++, bar, ngrp);
        for (int t = b; t < 256; t += nb)
            gemmW_phase<false, false>(t, 8, 16, UA, P.AOb, nullptr, 0, 512,
                P.dec_sa_out_w + (long)i * 512 * 512, 512, nullptr,
                P.SLAB, 512, 524288, 256, nullptr, 0, 256);
        gsync(inst++, bar, ngrp);
        for (int t = b; t < 256; t += nb)
            ln_phase<2>(t, P.Yf, P.SLAB, P.dec_sa_out_b + i * 512,
                        P.dec_ln1_s + i * 512, P.dec_ln1_b + i * 512, P.Yf, P.Yb);
        gsync(inst++, bar, ngrp);
        for (int t = b; t < 384; t += nb)
            gemmW_phase<false, true>(t, 24, 16, UA, P.Yb, P.MEMb, 512, 512,
                P.dec_ca_qkv_w + (long)i * 1536 * 512, 512, P.dec_ca_qkv_b + i * 1536,
                P.QKVb, 1536, 0, 512, P.VT, 1024, 0);
        gsync(inst++, bar, ngrp);
        for (int t = b; t < 128; t += nb) attn_phase(t, UA, P.QKVb, P.VT, P.AOb);
        gsync(inst++, bar, ngrp);
        for (int t = b; t < 256; t += nb)
            gemmW_phase<false, false>(t, 8, 16, UA, P.AOb, nullptr, 0, 512,
                P.dec_ca_out_w + (long)i * 512 * 512, 512, nullptr,
                P.SLAB, 512, 524288, 256, nullptr, 0, 256);
        gsync(inst++, bar, ngrp);
        for (int t = b; t < 256; t += nb)
            ln_phase<2>(t, P.Yf, P.SLAB, P.dec_ca_out_b + i * 512,
                        P.dec_ln2_s + i * 512, P.dec_ln2_b + i * 512, P.Yf, P.Yb);
        gsync(inst++, bar, ngrp);
        for (int t = b; t < 512; t += nb)
            gemmW_phase<true, true>(t, 32, 16, UA, P.Yb, nullptr, 0, 512,
                P.dec_ff1_w + (long)i * 2048 * 512, 512, P.dec_ff1_b + i * 2048,
                P.F1b, 2048, 0, 512, nullptr, 0, 0);
        gsync(inst++, bar, ngrp);
        for (int t = b; t < 512; t += nb)
            gemmW_phase<false, false>(t, 8, 16, UA, P.F1b, nullptr, 0, 2048,
                P.dec_ff2_w + (long)i * 512 * 2048, 2048, nullptr,
                P.SLAB, 512, 524288, 512, nullptr, 0, 512);
        gsync(inst++, bar, ngrp);
        for (int t = b; t < 256; t += nb)
            ln_phase<4>(t, P.Yf, P.SLAB, P.dec_ff2_b + i * 512,
                        P.dec_ln3_s + i * 512, P.dec_ln3_b + i * 512, P.Yf, P.Yb);
        gsync(inst++, bar, ngrp);
    }

    // ------------------------------ final ------------------------------------
    for (int t = b; t < 256; t += nb)
        lnl2_phase(t, P.Yf, P.dec_norm_s, P.dec_norm_b, P.out_attn, P.NBb);
    gsync(inst++, bar, ngrp);
    for (int t = b; t < 256; t += nb)
        gemmG_phase(t, UA, P.NBb, 512, P.NBb, 512, P.out_gram, 1024, 512);
}

// -------- init: zero barrier + x -> MEMf, Yf (fp32) + MEMb, Yb (bf16) --------
__global__ __launch_bounds__(256)
void init_k(const float* __restrict__ x, float* __restrict__ mf, float* __restrict__ yf,
            unsigned short* __restrict__ mb, unsigned short* __restrict__ yb,
            int* __restrict__ bar)
{
    if (blockIdx.x == 0) {
        for (int i = threadIdx.x; i < 1024; i += 256) bar[i] = 0;
    }
    const long i = ((long)blockIdx.x * 256 + threadIdx.x) * 4;
    const float4 v = *(const float4*)(x + i);
    *(float4*)(mf + i) = v;
    *(float4*)(yf + i) = v;
    short4v s;
    s[0] = (short)f2bu(v.x); s[1] = (short)f2bu(v.y);
    s[2] = (short)f2bu(v.z); s[3] = (short)f2bu(v.w);
    *(short4v*)(mb + i) = s;
    *(short4v*)(yb + i) = s;
}

// ------------------------------ host side ------------------------------------
extern "C" void kernel_launch(void* const* d_in, const int* in_sizes, int n_in,
                              void* d_out, int out_size, void* d_ws, size_t ws_size,
                              hipStream_t stream)
{
    char* p = (char*)d_ws;
    auto alloc = [&](size_t bytes) -> char* {
        char* r = p; p += (bytes + 255) & ~(size_t)255; return r;
    };
    int*            BAR  = (int*)alloc(4096);
    float*          MEMf = (float*)alloc(1024 * 512 * 4);
    float*          Yf   = (float*)alloc(1024 * 512 * 4);
    unsigned short* MEMb = (unsigned short*)alloc(1024 * 512 * 2);
    unsigned short* Yb   = (unsigned short*)alloc(1024 * 512 * 2);
    unsigned short* QKVb = (unsigned short*)alloc(1024 * 1536 * 2);
    unsigned short* VT   = (unsigned short*)alloc(8L * 64 * 1024 * 2);
    unsigned short* AOb  = (unsigned short*)alloc(1024 * 512 * 2);
    float*          SLAB = (float*)alloc(4L * 1024 * 512 * 4);
    unsigned short* F1b  = (unsigned short*)alloc(1024L * 2048 * 2);
    unsigned short* NBb  = (unsigned short*)alloc(1024 * 512 * 2);

    Params P;
    P.enc_qkv_w    = (const float*)d_in[1];  P.enc_qkv_b    = (const float*)d_in[2];
    P.enc_out_w    = (const float*)d_in[3];  P.enc_out_b    = (const float*)d_in[4];
    P.enc_ff1_w    = (const float*)d_in[5];  P.enc_ff1_b    = (const float*)d_in[6];
    P.enc_ff2_w    = (const float*)d_in[7];  P.enc_ff2_b    = (const float*)d_in[8];
    P.enc_ln1_s    = (const float*)d_in[9];  P.enc_ln1_b    = (const float*)d_in[10];
    P.enc_ln2_s    = (const float*)d_in[11]; P.enc_ln2_b    = (const float*)d_in[12];
    P.dec_sa_qkv_w = (const float*)d_in[13]; P.dec_sa_qkv_b = (const float*)d_in[14];
    P.dec_sa_out_w = (const float*)d_in[15]; P.dec_sa_out_b = (const float*)d_in[16];
    P.dec_ca_qkv_w = (const float*)d_in[17]; P.dec_ca_qkv_b = (const float*)d_in[18];
    P.dec_ca_out_w = (const float*)d_in[19]; P.dec_ca_out_b = (const float*)d_in[20];
    P.dec_ff1_w    = (const float*)d_in[21]; P.dec_ff1_b    = (const float*)d_in[22];
    P.dec_ff2_w    = (const float*)d_in[23]; P.dec_ff2_b    = (const float*)d_in[24];
    P.dec_ln1_s    = (const float*)d_in[25]; P.dec_ln1_b    = (const float*)d_in[26];
    P.dec_ln2_s    = (const float*)d_in[27]; P.dec_ln2_b    = (const float*)d_in[28];
    P.dec_ln3_s    = (const float*)d_in[29]; P.dec_ln3_b    = (const float*)d_in[30];
    P.enc_norm_s   = (const float*)d_in[31]; P.enc_norm_b   = (const float*)d_in[32];
    P.dec_norm_s   = (const float*)d_in[33]; P.dec_norm_b   = (const float*)d_in[34];
    P.MEMf = MEMf; P.Yf = Yf; P.SLAB = SLAB;
    P.MEMb = MEMb; P.Yb = Yb; P.QKVb = QKVb; P.VT = VT; P.AOb = AOb;
    P.F1b = F1b;   P.NBb = NBb;
    P.out_gram = (float*)d_out;
    P.out_attn = P.out_gram + 1024 * 1024;
    P.bar = BAR;

    // residency-safe grid size: blocks/CU from occupancy query (expect 2 -> 512)
    int occ = 1;
    (void)hipOccupancyMaxActiveBlocksPerMultiprocessor(&occ,
            reinterpret_cast<const void*>(mega_k), 256, 0);
    if (occ < 1) occ = 1;
    int nb = occ * 256;
    if (nb > 512) nb = 512;
    P.nb = nb;
    P.ngrp = nb / 32;

    init_k<<<512, 256, 0, stream>>>((const float*)d_in[0], MEMf, Yf, MEMb, Yb, BAR);
    mega_k<<<nb, 256, 0, stream>>>(P);
}

// Round 10
// 2188.591 us; speedup vs baseline: 1.5295x; 1.5293x over previous
//
#include <hip/hip_runtime.h>

// MyTransformer: 6-enc + 6-dec, S=1024, D=512, H=8x64, FF=2048.
// Round 9: round-5 dispatch flow + LN fused into split-K GEMMs via
// completion-counter epilogue (last-arriving block does the LN; no spinning).
// 81 dispatches (was 113). enc_norm / final LN+L2 folded into the FF2 epilogues.

#define NLAY 6

typedef __attribute__((ext_vector_type(8))) short short8;
typedef __attribute__((ext_vector_type(4))) short short4v;
typedef __attribute__((ext_vector_type(4))) float f32x4;

typedef __attribute__((address_space(3))) short lds_short;
typedef __attribute__((address_space(1))) const unsigned short g_ushort;

__device__ __forceinline__ void gload16(const unsigned short* g, short* l) {
    __builtin_amdgcn_global_load_lds((g_ushort*)g, (lds_short*)l, 16, 0, 0);
}

__device__ __forceinline__ void waitvm(int n) {   // wave-uniform literal waits
    if (n == 0)      asm volatile("s_waitcnt vmcnt(0)" ::: "memory");
    else if (n == 4) asm volatile("s_waitcnt vmcnt(4)" ::: "memory");
    else if (n == 8) asm volatile("s_waitcnt vmcnt(8)" ::: "memory");
    else             asm volatile("s_waitcnt vmcnt(12)" ::: "memory");
}

__device__ inline unsigned short f2bu(float x) {
    unsigned u = __builtin_bit_cast(unsigned, x);
    unsigned r = (u + 0x7fffu + ((u >> 16) & 1u)) >> 16;   // RNE
    return (unsigned short)r;
}

// ------------- fp32 -> bf16 weight cvt: flat balanced grid, 1 dispatch -------
struct WCvt {
    const float* src[10];
    unsigned short* dst[10];
    long cum[11];           // prefix sums in 8-element chunks
};

__global__ __launch_bounds__(256)
void f2ball_k(WCvt wc)
{
    const long total = wc.cum[10];
    for (long c = (long)blockIdx.x * 256 + threadIdx.x; c < total;
         c += (long)gridDim.x * 256) {
        int t = 0;
        #pragma unroll
        for (int i = 1; i < 10; ++i) if (c >= wc.cum[i]) t = i;
        const long o = (c - wc.cum[t]) * 8;
        const float* s = wc.src[t];
        unsigned short* d = wc.dst[t];
        const float4 a = *(const float4*)(s + o);
        const float4 b = *(const float4*)(s + o + 4);
        short8 v;
        v[0] = (short)f2bu(a.x); v[1] = (short)f2bu(a.y);
        v[2] = (short)f2bu(a.z); v[3] = (short)f2bu(a.w);
        v[4] = (short)f2bu(b.x); v[5] = (short)f2bu(b.y);
        v[6] = (short)f2bu(b.z); v[7] = (short)f2bu(b.w);
        *(short8*)(d + o) = v;
    }
}

__global__ __launch_bounds__(256)
void f2b_k(const float* __restrict__ s, unsigned short* __restrict__ d, long n)
{
    const long stride = (long)gridDim.x * 256;
    for (long i = (long)blockIdx.x * 256 + threadIdx.x; i * 8 < n; i += stride) {
        const long o = i * 8;
        const float4 a = *(const float4*)(s + o);
        const float4 b = *(const float4*)(s + o + 4);
        short8 v;
        v[0] = (short)f2bu(a.x); v[1] = (short)f2bu(a.y);
        v[2] = (short)f2bu(a.z); v[3] = (short)f2bu(a.w);
        v[4] = (short)f2bu(b.x); v[5] = (short)f2bu(b.y);
        v[6] = (short)f2bu(b.z); v[7] = (short)f2bu(b.w);
        *(short8*)(d + o) = v;
    }
}

// ---------------- 4-wave MFMA GEMM: C = alpha * A @ B^T + bias ---------------
// (round-5 proven kernel) 64x64 tile, BK=64, 5-buffer gload_lds pipeline.
template<bool RELU, bool OBF16>
__global__ __launch_bounds__(256)
void gemm5_k(const unsigned short* __restrict__ A,
             const unsigned short* __restrict__ A2, int a2_col,
             int lda, long sA,
             const unsigned short* __restrict__ B, int ldb, long sB,
             const float* __restrict__ bias,
             void* __restrict__ Cv, int ldc, long sC,
             int K, float alpha,
             unsigned short* __restrict__ VTp, int vt_col0, int kz)
{
    __shared__ __align__(16) short As[5][64 * 64];
    __shared__ __align__(16) short Bs[5][64 * 64];
    const int bz = blockIdx.z;
    const int m0 = blockIdx.y * 64;
    const int n0 = blockIdx.x * 64;
    if (A2 && n0 >= a2_col) A = A2;
    A += (long)bz * sA + (long)bz * kz;
    B += (long)bz * sB + (long)bz * kz;
    const int tid = threadIdx.x;
    const int w  = tid >> 6;
    const int l  = tid & 63;
    const int fr = l & 15;
    const int kc = l >> 4;

    f32x4 acc[4] = {};
    const int T = K >> 6;

    auto FILL = [&](int t, int buf) {
        const int k0 = t * 64;
        #pragma unroll
        for (int it = 0; it < 2; ++it) {
            const int row = w * 16 + it * 8 + (l >> 3);
            const int sl  = ((l & 7) ^ (row & 7)) * 8;
            gload16(A + (long)(m0 + row) * lda + k0 + sl, &As[buf][(w * 16 + it * 8) * 64]);
            gload16(B + (long)(n0 + row) * ldb + k0 + sl, &Bs[buf][(w * 16 + it * 8) * 64]);
        }
    };

    FILL(0, 0);
    if (T > 1) FILL(1, 1);
    if (T > 2) FILL(2, 2);
    if (T > 3) FILL(3, 3);
    int cb = 0, fb = 4;
    for (int t = 0; t < T; ++t) {
        const int rem = T - 1 - t;
        waitvm(rem >= 3 ? 12 : rem * 4);
        __builtin_amdgcn_sched_barrier(0);
        __builtin_amdgcn_s_barrier();
        if (t + 4 < T) FILL(t + 4, fb);
        fb = (fb == 4) ? 0 : fb + 1;
        #pragma unroll
        for (int ks = 0; ks < 2; ++ks) {
            const int arow = w * 16 + fr;
            const short8 af = *(const short8*)&As[cb][arow * 64 + (((ks * 4 + kc) ^ (arow & 7)) * 8)];
            #pragma unroll
            for (int c = 0; c < 4; ++c) {
                const int brow = c * 16 + fr;
                const short8 bf = *(const short8*)&Bs[cb][brow * 64 + (((ks * 4 + kc) ^ (brow & 7)) * 8)];
                acc[c] = __builtin_amdgcn_mfma_f32_16x16x32_bf16(af, bf, acc[c], 0, 0, 0);
            }
        }
        cb = (cb == 4) ? 0 : cb + 1;
    }

    #pragma unroll
    for (int c = 0; c < 4; ++c) {
        const int n = n0 + c * 16 + fr;
        const float bv = bias ? bias[n] : 0.0f;
        const bool do_vt = (VTp != nullptr) && (n >= vt_col0);
        #pragma unroll
        for (int i = 0; i < 4; ++i) {
            const long m = m0 + w * 16 + kc * 4 + i;
            float v = acc[c][i] * alpha + bv;
            if (RELU) v = fmaxf(v, 0.0f);
            if (OBF16) ((unsigned short*)Cv)[bz * sC + m * ldc + n] = f2bu(v);
            else       ((float*)Cv)[bz * sC + m * ldc + n] = v;
            if (do_vt) {
                const int vc = n - vt_col0;
                VTp[(long)(vc >> 6) * 65536 + (long)(vc & 63) * 1024 + m] = f2bu(v);
            }
        }
    }
}

// ------ split-K GEMM (N=512) + fused LN epilogue via completion counter ------
// Grid (8, 16, NSLAB). Each z computes K-slice Ksub into slab z. After the slab
// write, blocks atomically count per row-group; the LAST block (no spin) does
// LN(x + sum slabs + gbias)*lns + lnb for its 64 rows.
// FIN=0: write outf(fp32)+outb(bf16). FIN=1: second LN (s2,b2) -> outb only.
// FIN=2: second LN -> oattn(fp32) + row-L2-normalize -> nbb(bf16).
template<int NSLAB, int FIN>
__global__ __launch_bounds__(256)
void gemmLN_k(const unsigned short* __restrict__ A, int lda,
              const unsigned short* __restrict__ B, int ldb,
              float* __restrict__ SLABp, int Ksub,
              int* __restrict__ cnt,
              const float* __restrict__ xf, const float* __restrict__ gbias,
              const float* __restrict__ lns, const float* __restrict__ lnb,
              float* __restrict__ outf, unsigned short* __restrict__ outb,
              const float* __restrict__ s2p, const float* __restrict__ b2p,
              float* __restrict__ oattn, unsigned short* __restrict__ nbb)
{
    __shared__ __align__(16) short As[5][64 * 64];
    __shared__ __align__(16) short Bs[5][64 * 64];
    __shared__ int lastflag;
    const int bz = blockIdx.z;
    const int m0 = blockIdx.y * 64;
    const int n0 = blockIdx.x * 64;
    const unsigned short* Ab = A + (long)bz * Ksub;
    const unsigned short* Bb = B + (long)bz * Ksub;
    float* C = SLABp + (long)bz * 524288;
    const int tid = threadIdx.x;
    const int w  = tid >> 6;
    const int l  = tid & 63;
    const int fr = l & 15;
    const int kc = l >> 4;

    f32x4 acc[4] = {};
    const int T = Ksub >> 6;

    auto FILL = [&](int t, int buf) {
        const int k0 = t * 64;
        #pragma unroll
        for (int it = 0; it < 2; ++it) {
            const int row = w * 16 + it * 8 + (l >> 3);
            const int sl  = ((l & 7) ^ (row & 7)) * 8;
            gload16(Ab + (long)(m0 + row) * lda + k0 + sl, &As[buf][(w * 16 + it * 8) * 64]);
            gload16(Bb + (long)(n0 + row) * ldb + k0 + sl, &Bs[buf][(w * 16 + it * 8) * 64]);
        }
    };

    FILL(0, 0);
    if (T > 1) FILL(1, 1);
    if (T > 2) FILL(2, 2);
    if (T > 3) FILL(3, 3);
    int cb = 0, fb = 4;
    for (int t = 0; t < T; ++t) {
        const int rem = T - 1 - t;
        waitvm(rem >= 3 ? 12 : rem * 4);
        __builtin_amdgcn_sched_barrier(0);
        __builtin_amdgcn_s_barrier();
        if (t + 4 < T) FILL(t + 4, fb);
        fb = (fb == 4) ? 0 : fb + 1;
        #pragma unroll
        for (int ks = 0; ks < 2; ++ks) {
            const int arow = w * 16 + fr;
            const short8 af = *(const short8*)&As[cb][arow * 64 + (((ks * 4 + kc) ^ (arow & 7)) * 8)];
            #pragma unroll
            for (int c = 0; c < 4; ++c) {
                const int brow = c * 16 + fr;
                const short8 bf = *(const short8*)&Bs[cb][brow * 64 + (((ks * 4 + kc) ^ (brow & 7)) * 8)];
                acc[c] = __builtin_amdgcn_mfma_f32_16x16x32_bf16(af, bf, acc[c], 0, 0, 0);
            }
        }
        cb = (cb == 4) ? 0 : cb + 1;
    }

    #pragma unroll
    for (int c = 0; c < 4; ++c) {
        const int n = n0 + c * 16 + fr;
        #pragma unroll
        for (int i = 0; i < 4; ++i) {
            const long m = m0 + w * 16 + kc * 4 + i;
            C[m * 512 + n] = acc[c][i];
        }
    }

    // ---- completion handshake: last block per row-group does the LN ----
    __syncthreads();
    if (tid == 0) {
        __threadfence();   // release: make this block's slab writes visible
        const int old = __hip_atomic_fetch_add(&cnt[blockIdx.y], 1,
                          __ATOMIC_ACQ_REL, __HIP_MEMORY_SCOPE_AGENT);
        lastflag = (old == 8 * NSLAB - 1) ? 1 : 0;
        if (lastflag) __threadfence();   // acquire: invalidate before reading peers
    }
    __syncthreads();
    if (!lastflag) return;

    // LN for rows m0..m0+63 (wave w handles rows m0+w*16 .. +15, one per iter)
    const int lane = l;
    for (int it = 0; it < 16; ++it) {
        const int row = m0 + w * 16 + it;
        const long base = (long)row * 512;
        float v[8];
        float sum = 0.f;
        #pragma unroll
        for (int i = 0; i < 8; ++i) {
            const int j = lane + (i << 6);
            v[i] = xf[base + j];
            #pragma unroll
            for (int t = 0; t < NSLAB; ++t) v[i] += SLABp[(long)t * 524288 + base + j];
            v[i] += gbias[j];
            sum += v[i];
        }
        #pragma unroll
        for (int off = 32; off; off >>= 1) sum += __shfl_xor(sum, off);
        const float mn = sum * (1.0f / 512.0f);
        float q = 0.f;
        #pragma unroll
        for (int i = 0; i < 8; ++i) { const float d = v[i] - mn; q += d * d; }
        #pragma unroll
        for (int off = 32; off; off >>= 1) q += __shfl_xor(q, off);
        const float inv = rsqrtf(q * (1.0f / 512.0f) + 1e-5f);
        float r[8];
        #pragma unroll
        for (int i = 0; i < 8; ++i) {
            const int j = lane + (i << 6);
            r[i] = (v[i] - mn) * inv * lns[j] + lnb[j];
        }
        if (FIN == 0) {
            #pragma unroll
            for (int i = 0; i < 8; ++i) {
                const int j = lane + (i << 6);
                outf[base + j] = r[i];
                outb[base + j] = f2bu(r[i]);
            }
        } else {
            float sum2 = 0.f;
            #pragma unroll
            for (int i = 0; i < 8; ++i) sum2 += r[i];
            #pragma unroll
            for (int off = 32; off; off >>= 1) sum2 += __shfl_xor(sum2, off);
            const float mn2 = sum2 * (1.0f / 512.0f);
            float q2 = 0.f;
            #pragma unroll
            for (int i = 0; i < 8; ++i) { const float d = r[i] - mn2; q2 += d * d; }
            #pragma unroll
            for (int off = 32; off; off >>= 1) q2 += __shfl_xor(q2, off);
            const float inv2 = rsqrtf(q2 * (1.0f / 512.0f) + 1e-5f);
            if (FIN == 1) {
                #pragma unroll
                for (int i = 0; i < 8; ++i) {
                    const int j = lane + (i << 6);
                    const float r2 = (r[i] - mn2) * inv2 * s2p[j] + b2p[j];
                    outb[base + j] = f2bu(r2);   // final enc MEMb (decoder K/V)
                }
            } else {
                float r2a[8];
                float nrm = 0.f;
                #pragma unroll
                for (int i = 0; i < 8; ++i) {
                    const int j = lane + (i << 6);
                    r2a[i] = (r[i] - mn2) * inv2 * s2p[j] + b2p[j];
                    oattn[base + j] = r2a[i];
                    nrm += r2a[i] * r2a[i];
                }
                #pragma unroll
                for (int off = 32; off; off >>= 1) nrm += __shfl_xor(nrm, off);
                const float rinv = rsqrtf(nrm);
                #pragma unroll
                for (int i = 0; i < 8; ++i)
                    nbb[base + (lane + (i << 6))] = f2bu(r2a[i] * rinv);
            }
        }
    }
}

// ---------------- fused attention: O = softmax(QK^T/8) V ---------------------
// (round-5 proven kernel) Grid (32 q-tiles of 32 rows, 8 heads), 128 thr.
__global__ __launch_bounds__(128)
void attn_k(const unsigned short* __restrict__ QKVb,   // [1024][1536]
            const unsigned short* __restrict__ VT,     // [8][64][1024]
            unsigned short* __restrict__ AOb)          // [1024][512]
{
    __shared__ __align__(16) short Ks[3][64 * 64];
    __shared__ __align__(16) short Vs[3][64 * 64];
    __shared__ __align__(16) short Ps[2][16 * 64];
    const int qt = blockIdx.x;
    const int h  = blockIdx.y;
    const int tid = threadIdx.x;
    const int w  = tid >> 6;
    const int l  = tid & 63;
    const int fr = l & 15;
    const int kc = l >> 4;

    const int qrow = qt * 32 + w * 16 + fr;
    short8 qf[2];
    qf[0] = *(const short8*)(QKVb + (long)qrow * 1536 + h * 64 + kc * 8);
    qf[1] = *(const short8*)(QKVb + (long)qrow * 1536 + h * 64 + 32 + kc * 8);

    auto FILL = [&](int t, int buf) {
        const int kb = t * 64;
        #pragma unroll
        for (int it = 0; it < 4; ++it) {
            const int row = it * 16 + w * 8 + (l >> 3);
            const int sl  = ((l & 7) ^ (row & 7)) * 8;
            gload16(QKVb + (long)(kb + row) * 1536 + 512 + h * 64 + sl,
                    &Ks[buf][(it * 16 + w * 8) * 64]);
            gload16(VT + (long)h * 65536 + (long)row * 1024 + kb + sl,
                    &Vs[buf][(it * 16 + w * 8) * 64]);
        }
    };

    float m_i[4], l_i[4];
    f32x4 acc_o[4] = {};
    #pragma unroll
    for (int i = 0; i < 4; ++i) { m_i[i] = -1e30f; l_i[i] = 0.f; }

    short* ps = &Ps[w][0];

    FILL(0, 0); FILL(1, 1);
    int fb = 2, cb = 0;
    for (int t = 0; t < 16; ++t) {
        waitvm(t == 15 ? 0 : 8);
        __builtin_amdgcn_sched_barrier(0);
        __builtin_amdgcn_s_barrier();
        if (t + 2 < 16) { FILL(t + 2, fb); fb = (fb == 2) ? 0 : fb + 1; }

        f32x4 sacc[4] = {};
        #pragma unroll
        for (int ks = 0; ks < 2; ++ks) {
            #pragma unroll
            for (int c = 0; c < 4; ++c) {
                const int krow = c * 16 + fr;
                const short8 kf = *(const short8*)&Ks[cb][krow * 64 + (((ks * 4 + kc) ^ (krow & 7)) * 8)];
                sacc[c] = __builtin_amdgcn_mfma_f32_16x16x32_bf16(qf[ks], kf, sacc[c], 0, 0, 0);
            }
        }

        float p[4][4];
        #pragma unroll
        for (int i = 0; i < 4; ++i) {
            float tm = fmaxf(fmaxf(sacc[0][i], sacc[1][i]), fmaxf(sacc[2][i], sacc[3][i]));
            #pragma unroll
            for (int off = 8; off; off >>= 1) tm = fmaxf(tm, __shfl_xor(tm, off));
            tm *= 0.125f;
            const float mn = fmaxf(m_i[i], tm);
            const float sc = __expf(m_i[i] - mn);
            m_i[i] = mn;
            float ts = 0.f;
            #pragma unroll
            for (int c = 0; c < 4; ++c) { p[c][i] = __expf(sacc[c][i] * 0.125f - mn); ts += p[c][i]; }
            #pragma unroll
            for (int off = 8; off; off >>= 1) ts += __shfl_xor(ts, off);
            l_i[i] = l_i[i] * sc + ts;
            #pragma unroll
            for (int c = 0; c < 4; ++c) acc_o[c][i] *= sc;
        }

        #pragma unroll
        for (int c = 0; c < 4; ++c) {
            const int col = c * 16 + fr;
            #pragma unroll
            for (int i = 0; i < 4; ++i) {
                const int row = kc * 4 + i;
                ps[row * 64 + (((col >> 3) ^ (row & 7)) * 8) + (col & 7)] = (short)f2bu(p[c][i]);
            }
        }
        short8 pf[2];
        pf[0] = *(const short8*)&ps[fr * 64 + ((kc ^ (fr & 7)) * 8)];
        pf[1] = *(const short8*)&ps[fr * 64 + (((4 + kc) ^ (fr & 7)) * 8)];

        #pragma unroll
        for (int ks = 0; ks < 2; ++ks) {
            #pragma unroll
            for (int c = 0; c < 4; ++c) {
                const int drow = c * 16 + fr;
                const short8 vf = *(const short8*)&Vs[cb][drow * 64 + (((ks * 4 + kc) ^ (drow & 7)) * 8)];
                acc_o[c] = __builtin_amdgcn_mfma_f32_16x16x32_bf16(pf[ks], vf, acc_o[c], 0, 0, 0);
            }
        }
        cb = (cb == 2) ? 0 : cb + 1;
    }

    #pragma unroll
    for (int c = 0; c < 4; ++c) {
        const int dcol = h * 64 + c * 16 + fr;
        #pragma unroll
        for (int i = 0; i < 4; ++i) {
            const int row = qt * 32 + w * 16 + kc * 4 + i;
            AOb[(long)row * 512 + dcol] = f2bu(acc_o[c][i] / l_i[i]);
        }
    }
}

// -------- init: zero counters + x -> MEMf, Yf (fp32) + MEMb, Yb (bf16) -------
__global__ __launch_bounds__(256)
void init_k(const float* __restrict__ x, float* __restrict__ mf, float* __restrict__ yf,
            unsigned short* __restrict__ mb, unsigned short* __restrict__ yb,
            int* __restrict__ cnt)
{
    if (blockIdx.x == 0) {
        for (int i = threadIdx.x; i < 512; i += 256) cnt[i] = 0;
    }
    const long i = ((long)blockIdx.x * 256 + threadIdx.x) * 4;
    const float4 v = *(const float4*)(x + i);
    *(float4*)(mf + i) = v;
    *(float4*)(yf + i) = v;
    short4v s;
    s[0] = (short)f2bu(v.x); s[1] = (short)f2bu(v.y);
    s[2] = (short)f2bu(v.z); s[3] = (short)f2bu(v.w);
    *(short4v*)(mb + i) = s;
    *(short4v*)(yb + i) = s;
}

// ------------------------------ host side ------------------------------------
static void gemm5(hipStream_t st, bool relu, bool obf16,
                  const unsigned short* A, int lda, long sA,
                  const unsigned short* B, int ldb, long sB,
                  const float* bias, void* C, int ldc, long sC,
                  int M, int N, int K, float alpha, int batch,
                  unsigned short* VTp = nullptr, int vt_col0 = 0,
                  const unsigned short* A2 = nullptr, int a2_col = 0,
                  int kz = 0)
{
    dim3 g(N / 64, M / 64, batch);
    if (obf16) {
        if (relu) gemm5_k<true,  true ><<<g, 256, 0, st>>>(A, A2, a2_col, lda, sA, B, ldb, sB, bias, C, ldc, sC, K, alpha, VTp, vt_col0, kz);
        else      gemm5_k<false, true ><<<g, 256, 0, st>>>(A, A2, a2_col, lda, sA, B, ldb, sB, bias, C, ldc, sC, K, alpha, VTp, vt_col0, kz);
    } else {
        if (relu) gemm5_k<true,  false><<<g, 256, 0, st>>>(A, A2, a2_col, lda, sA, B, ldb, sB, bias, C, ldc, sC, K, alpha, VTp, vt_col0, kz);
        else      gemm5_k<false, false><<<g, 256, 0, st>>>(A, A2, a2_col, lda, sA, B, ldb, sB, bias, C, ldc, sC, K, alpha, VTp, vt_col0, kz);
    }
}

extern "C" void kernel_launch(void* const* d_in, const int* in_sizes, int n_in,
                              void* d_out, int out_size, void* d_ws, size_t ws_size,
                              hipStream_t stream)
{
    const float* x            = (const float*)d_in[0];
    const float* enc_qkv_w    = (const float*)d_in[1];
    const float* enc_qkv_b    = (const float*)d_in[2];
    const float* enc_out_w    = (const float*)d_in[3];
    const float* enc_out_b    = (const float*)d_in[4];
    const float* enc_ff1_w    = (const float*)d_in[5];
    const float* enc_ff1_b    = (const float*)d_in[6];
    const float* enc_ff2_w    = (const float*)d_in[7];
    const float* enc_ff2_b    = (const float*)d_in[8];
    const float* enc_ln1_s    = (const float*)d_in[9];
    const float* enc_ln1_b    = (const float*)d_in[10];
    const float* enc_ln2_s    = (const float*)d_in[11];
    const float* enc_ln2_b    = (const float*)d_in[12];
    const float* dec_sa_qkv_w = (const float*)d_in[13];
    const float* dec_sa_qkv_b = (const float*)d_in[14];
    const float* dec_sa_out_w = (const float*)d_in[15];
    const float* dec_sa_out_b = (const float*)d_in[16];
    const float* dec_ca_qkv_w = (const float*)d_in[17];
    const float* dec_ca_qkv_b = (const float*)d_in[18];
    const float* dec_ca_out_w = (const float*)d_in[19];
    const float* dec_ca_out_b = (const float*)d_in[20];
    const float* dec_ff1_w    = (const float*)d_in[21];
    const float* dec_ff1_b    = (const float*)d_in[22];
    const float* dec_ff2_w    = (const float*)d_in[23];
    const float* dec_ff2_b    = (const float*)d_in[24];
    const float* dec_ln1_s    = (const float*)d_in[25];
    const float* dec_ln1_b    = (const float*)d_in[26];
    const float* dec_ln2_s    = (const float*)d_in[27];
    const float* dec_ln2_b    = (const float*)d_in[28];
    const float* dec_ln3_s    = (const float*)d_in[29];
    const float* dec_ln3_b    = (const float*)d_in[30];
    const float* enc_norm_s   = (const float*)d_in[31];
    const float* enc_norm_b   = (const float*)d_in[32];
    const float* dec_norm_s   = (const float*)d_in[33];
    const float* dec_norm_b   = (const float*)d_in[34];

    char* p = (char*)d_ws;
    auto alloc = [&](size_t bytes) -> char* {
        char* r = p; p += (bytes + 255) & ~(size_t)255; return r;
    };
    int*            CNT  = (int*)alloc(512 * 4);
    float*          MEMf = (float*)alloc(1024 * 512 * 4);
    float*          Yf   = (float*)alloc(1024 * 512 * 4);
    unsigned short* MEMb = (unsigned short*)alloc(1024 * 512 * 2);
    unsigned short* Yb   = (unsigned short*)alloc(1024 * 512 * 2);
    unsigned short* QKVb = (unsigned short*)alloc(1024 * 1536 * 2);
    unsigned short* VT   = (unsigned short*)alloc(8L * 64 * 1024 * 2);
    unsigned short* AOb  = (unsigned short*)alloc(1024 * 512 * 2);
    float*          SLAB = (float*)alloc(4L * 1024 * 512 * 4);
    unsigned short* F1b  = (unsigned short*)alloc(1024L * 2048 * 2);
    unsigned short* NBb  = (unsigned short*)alloc(1024 * 512 * 2);

    const float* wsrc[10] = {enc_qkv_w, enc_out_w, enc_ff1_w, enc_ff2_w,
                             dec_sa_qkv_w, dec_sa_out_w, dec_ca_qkv_w, dec_ca_out_w,
                             dec_ff1_w, dec_ff2_w};
    const long wper[10] = {1536L*512, 512L*512, 2048L*512, 512L*2048,
                           1536L*512, 512L*512, 1536L*512, 512L*512,
                           2048L*512, 512L*2048};
    long wtot = 0;
    for (int t = 0; t < 10; ++t) wtot += wper[t] * NLAY;

    const size_t used = (size_t)(p - (char*)d_ws);
    const bool preconv = (ws_size > used) && ((ws_size - used) >= (size_t)wtot * 2 + 4096);

    unsigned short* wpre[10] = {};
    unsigned short* slots[2] = {};
    int slot_ctr = 0;
    if (preconv) {
        WCvt wc;
        wc.cum[0] = 0;
        for (int t = 0; t < 10; ++t) {
            wpre[t] = (unsigned short*)alloc((size_t)wper[t] * NLAY * 2);
            wc.src[t] = wsrc[t];
            wc.dst[t] = wpre[t];
            wc.cum[t + 1] = wc.cum[t] + wper[t] * NLAY / 8;
        }
        f2ball_k<<<dim3(2048), 256, 0, stream>>>(wc);
    } else {
        slots[0] = (unsigned short*)alloc(2048L * 512 * 2);
        slots[1] = (unsigned short*)alloc(2048L * 512 * 2);
    }
    auto W = [&](int t, int layer) -> const unsigned short* {
        if (preconv) return wpre[t] + (long)layer * wper[t];
        unsigned short* dst = slots[(slot_ctr++) & 1];
        const long n = wper[t];
        long blocks = (n / 8 + 255) / 256; if (blocks > 2048) blocks = 2048;
        f2b_k<<<dim3((unsigned)blocks), 256, 0, stream>>>(wsrc[t] + (long)layer * wper[t], dst, n);
        return dst;
    };

    float* out_gram = (float*)d_out;
    float* out_attn = out_gram + 1024 * 1024;

    int lnInst = 0;

    // split-K proj (NSLAB=2) + fused LN
    auto projLN = [&](const unsigned short* Aop, const unsigned short* Bw,
                      const float* xf, const float* gbias,
                      const float* lns, const float* lnb,
                      float* outf, unsigned short* outb) {
        gemmLN_k<2, 0><<<dim3(8, 16, 2), 256, 0, stream>>>(
            Aop, 512, Bw, 512, SLAB, 256, CNT + (lnInst++) * 16,
            xf, gbias, lns, lnb, outf, outb, nullptr, nullptr, nullptr, nullptr);
    };
    // split-K FF2 (NSLAB=4) + fused LN (+optional final LN variants)
    auto ff2LN = [&](const unsigned short* Bw, const float* xf, const float* gbias,
                     const float* lns, const float* lnb,
                     float* outf, unsigned short* outb, int fin,
                     const float* s2, const float* b2) {
        int* c = CNT + (lnInst++) * 16;
        if (fin == 0)
            gemmLN_k<4, 0><<<dim3(8, 16, 4), 256, 0, stream>>>(
                F1b, 2048, Bw, 2048, SLAB, 512, c, xf, gbias, lns, lnb,
                outf, outb, nullptr, nullptr, nullptr, nullptr);
        else if (fin == 1)
            gemmLN_k<4, 1><<<dim3(8, 16, 4), 256, 0, stream>>>(
                F1b, 2048, Bw, 2048, SLAB, 512, c, xf, gbias, lns, lnb,
                outf, outb, s2, b2, nullptr, nullptr);
        else
            gemmLN_k<4, 2><<<dim3(8, 16, 4), 256, 0, stream>>>(
                F1b, 2048, Bw, 2048, SLAB, 512, c, xf, gbias, lns, lnb,
                outf, outb, s2, b2, out_attn, NBb);
    };

    init_k<<<512, 256, 0, stream>>>(x, MEMf, Yf, MEMb, Yb, CNT);

    // ----------------------------- encoder -----------------------------------
    for (int i = 0; i < NLAY; ++i) {
        gemm5(stream, false, true, MEMb, 512, 0, W(0, i), 512, 0, enc_qkv_b + i * 1536,
              QKVb, 1536, 0, 1024, 1536, 512, 1.0f, 1, VT, 1024);
        attn_k<<<dim3(32, 8), 128, 0, stream>>>(QKVb, VT, AOb);
        projLN(AOb, W(1, i), MEMf, enc_out_b + i * 512,
               enc_ln1_s + i * 512, enc_ln1_b + i * 512, MEMf, MEMb);
        gemm5(stream, true, true, MEMb, 512, 0, W(2, i), 512, 0, enc_ff1_b + i * 2048,
              F1b, 2048, 0, 1024, 2048, 512, 1.0f, 1);
        ff2LN(W(3, i), MEMf, enc_ff2_b + i * 512,
              enc_ln2_s + i * 512, enc_ln2_b + i * 512, MEMf, MEMb,
              (i == NLAY - 1) ? 1 : 0, enc_norm_s, enc_norm_b);
    }

    // ----------------------------- decoder -----------------------------------
    for (int i = 0; i < NLAY; ++i) {
        gemm5(stream, false, true, Yb, 512, 0, W(4, i), 512, 0, dec_sa_qkv_b + i * 1536,
              QKVb, 1536, 0, 1024, 1536, 512, 1.0f, 1, VT, 1024);
        attn_k<<<dim3(32, 8), 128, 0, stream>>>(QKVb, VT, AOb);
        projLN(AOb, W(5, i), Yf, dec_sa_out_b + i * 512,
               dec_ln1_s + i * 512, dec_ln1_b + i * 512, Yf, Yb);

        gemm5(stream, false, true, Yb, 512, 0, W(6, i), 512, 0, dec_ca_qkv_b + i * 1536,
              QKVb, 1536, 0, 1024, 1536, 512, 1.0f, 1, VT, 1024, MEMb, 512);
        attn_k<<<dim3(32, 8), 128, 0, stream>>>(QKVb, VT, AOb);
        projLN(AOb, W(7, i), Yf, dec_ca_out_b + i * 512,
               dec_ln2_s + i * 512, dec_ln2_b + i * 512, Yf, Yb);

        gemm5(stream, true, true, Yb, 512, 0, W(8, i), 512, 0, dec_ff1_b + i * 2048,
              F1b, 2048, 0, 1024, 2048, 512, 1.0f, 1);
        ff2LN(W(9, i), Yf, dec_ff2_b + i * 512,
              dec_ln3_s + i * 512, dec_ln3_b + i * 512, Yf, Yb,
              (i == NLAY - 1) ? 2 : 0, dec_norm_s, dec_norm_b);
    }

    // gram = n @ n^T
    gemm5(stream, false, false, NBb, 512, 0, NBb, 512, 0, nullptr,
          out_gram, 1024, 0, 1024, 1024, 512, 1.0f, 1);
}

// Round 11
// 1170.003 us; speedup vs baseline: 2.8610x; 1.8706x over previous
//
#include <hip/hip_runtime.h>

// MyTransformer: 6-enc + 6-dec, S=1024, D=512, H=8x64, FF=2048.
// Round 10: round-5 dispatch flow; out-projection fused into attention
// (per-head slabs, race-free, no fences); GEMM 3-buf 48KB (3 blocks/CU);
// attn 2-buf 36KB (4 blocks/CU); LN<8>/<4> slab-merge; 95 dispatches.

#define NLAY 6

typedef __attribute__((ext_vector_type(8))) short short8;
typedef __attribute__((ext_vector_type(4))) short short4v;
typedef __attribute__((ext_vector_type(4))) float f32x4;

typedef __attribute__((address_space(3))) short lds_short;
typedef __attribute__((address_space(1))) const unsigned short g_ushort;

__device__ __forceinline__ void gload16(const unsigned short* g, short* l) {
    __builtin_amdgcn_global_load_lds((g_ushort*)g, (lds_short*)l, 16, 0, 0);
}

__device__ __forceinline__ void waitvm(int n) {   // wave-uniform literal waits
    if (n == 0)      asm volatile("s_waitcnt vmcnt(0)" ::: "memory");
    else if (n == 4) asm volatile("s_waitcnt vmcnt(4)" ::: "memory");
    else             asm volatile("s_waitcnt vmcnt(8)" ::: "memory");
}

__device__ inline unsigned short f2bu(float x) {
    unsigned u = __builtin_bit_cast(unsigned, x);
    unsigned r = (u + 0x7fffu + ((u >> 16) & 1u)) >> 16;   // RNE
    return (unsigned short)r;
}

// ------------- fp32 -> bf16 weight cvt: flat balanced grid, 1 dispatch -------
struct WCvt {
    const float* src[10];
    unsigned short* dst[10];
    long cum[11];           // prefix sums in 8-element chunks
};

__global__ __launch_bounds__(256)
void f2ball_k(WCvt wc)
{
    const long total = wc.cum[10];
    for (long c = (long)blockIdx.x * 256 + threadIdx.x; c < total;
         c += (long)gridDim.x * 256) {
        int t = 0;
        #pragma unroll
        for (int i = 1; i < 10; ++i) if (c >= wc.cum[i]) t = i;
        const long o = (c - wc.cum[t]) * 8;
        const float* s = wc.src[t];
        unsigned short* d = wc.dst[t];
        const float4 a = *(const float4*)(s + o);
        const float4 b = *(const float4*)(s + o + 4);
        short8 v;
        v[0] = (short)f2bu(a.x); v[1] = (short)f2bu(a.y);
        v[2] = (short)f2bu(a.z); v[3] = (short)f2bu(a.w);
        v[4] = (short)f2bu(b.x); v[5] = (short)f2bu(b.y);
        v[6] = (short)f2bu(b.z); v[7] = (short)f2bu(b.w);
        *(short8*)(d + o) = v;
    }
}

__global__ __launch_bounds__(256)
void f2b_k(const float* __restrict__ s, unsigned short* __restrict__ d, long n)
{
    const long stride = (long)gridDim.x * 256;
    for (long i = (long)blockIdx.x * 256 + threadIdx.x; i * 8 < n; i += stride) {
        const long o = i * 8;
        const float4 a = *(const float4*)(s + o);
        const float4 b = *(const float4*)(s + o + 4);
        short8 v;
        v[0] = (short)f2bu(a.x); v[1] = (short)f2bu(a.y);
        v[2] = (short)f2bu(a.z); v[3] = (short)f2bu(a.w);
        v[4] = (short)f2bu(b.x); v[5] = (short)f2bu(b.y);
        v[6] = (short)f2bu(b.z); v[7] = (short)f2bu(b.w);
        *(short8*)(d + o) = v;
    }
}

// ---------------- 4-wave MFMA GEMM: C = alpha * A @ B^T + bias ---------------
// 64x64 tile, BK=64, 3-buffer gload_lds pipeline (48 KB LDS -> 3 blocks/CU).
// Split-K via kz (element offset per z), slab out via sC. A2: merged QKV.
// VTp: V-transpose scatter for cols >= vt_col0.
template<bool RELU, bool OBF16>
__global__ __launch_bounds__(256)
void gemm3_k(const unsigned short* __restrict__ A,
             const unsigned short* __restrict__ A2, int a2_col, int lda,
             const unsigned short* __restrict__ B, int ldb,
             const float* __restrict__ bias,
             void* __restrict__ Cv, int ldc, long sC,
             int K, float alpha,
             unsigned short* __restrict__ VTp, int vt_col0, int kz)
{
    __shared__ __align__(16) short As[3][4096];
    __shared__ __align__(16) short Bs[3][4096];
    const int bz = blockIdx.z;
    const int m0 = blockIdx.y * 64;
    const int n0 = blockIdx.x * 64;
    if (A2 && n0 >= a2_col) A = A2;
    A += (long)bz * kz;
    B += (long)bz * kz;
    const int tid = threadIdx.x;
    const int w  = tid >> 6;
    const int l  = tid & 63;
    const int fr = l & 15;
    const int kc = l >> 4;

    f32x4 acc[4] = {};
    const int T = K >> 6;

    auto FILL = [&](int t, int buf) {
        const int k0 = t * 64;
        #pragma unroll
        for (int it = 0; it < 2; ++it) {
            const int row = w * 16 + it * 8 + (l >> 3);
            const int sl  = ((l & 7) ^ (row & 7)) * 8;
            gload16(A + (long)(m0 + row) * lda + k0 + sl, &As[buf][(w * 16 + it * 8) * 64]);
            gload16(B + (long)(n0 + row) * ldb + k0 + sl, &Bs[buf][(w * 16 + it * 8) * 64]);
        }
    };

    FILL(0, 0);
    if (T > 1) FILL(1, 1);
    for (int t = 0; t < T; ++t) {
        waitvm(t + 1 < T ? 4 : 0);
        __builtin_amdgcn_sched_barrier(0);
        __builtin_amdgcn_s_barrier();
        if (t + 2 < T) FILL(t + 2, (t + 2) % 3);
        const int cb = t % 3;
        #pragma unroll
        for (int ks = 0; ks < 2; ++ks) {
            const int arow = w * 16 + fr;
            const short8 af = *(const short8*)&As[cb][arow * 64 + (((ks * 4 + kc) ^ (arow & 7)) * 8)];
            #pragma unroll
            for (int c = 0; c < 4; ++c) {
                const int brow = c * 16 + fr;
                const short8 bf = *(const short8*)&Bs[cb][brow * 64 + (((ks * 4 + kc) ^ (brow & 7)) * 8)];
                acc[c] = __builtin_amdgcn_mfma_f32_16x16x32_bf16(af, bf, acc[c], 0, 0, 0);
            }
        }
    }

    #pragma unroll
    for (int c = 0; c < 4; ++c) {
        const int n = n0 + c * 16 + fr;
        const float bv = bias ? bias[n] : 0.0f;
        const bool do_vt = (VTp != nullptr) && (n >= vt_col0);
        #pragma unroll
        for (int i = 0; i < 4; ++i) {
            const long m = m0 + w * 16 + kc * 4 + i;
            float v = acc[c][i] * alpha + bv;
            if (RELU) v = fmaxf(v, 0.0f);
            if (OBF16) ((unsigned short*)Cv)[bz * sC + m * ldc + n] = f2bu(v);
            else       ((float*)Cv)[bz * sC + m * ldc + n] = v;
            if (do_vt) {
                const int vc = n - vt_col0;
                VTp[(long)(vc >> 6) * 65536 + (long)(vc & 63) * 1024 + m] = f2bu(v);
            }
        }
    }
}

// ------- fused attention + out-projection: SLAB[h] = (softmax(QK^T/8)V) Wo_h^T
// Grid (32 q-tiles of 32 rows, 8 heads), 128 thr = 2 waves. 2-buf K/V (36 KB).
// Epilogue: O -> LDS A-frags (P-trick), Wo 64x64 chunks double-buffered into
// the retired K region, 8 chunk-GEMMs write the per-head fp32 slab (race-free).
__global__ __launch_bounds__(128)
void attnp_k(const unsigned short* __restrict__ QKVb,   // [1024][1536]
             const unsigned short* __restrict__ VT,     // [8][64][1024]
             const unsigned short* __restrict__ wo,     // [512][512] bf16
             float* __restrict__ SLABp)                 // 8 x [1024][512] f32
{
    __shared__ __align__(16) short U[18432];   // 36 KB
    short* Ks = U;            // 2 x 4096
    short* Vs = U + 8192;     // 2 x 4096
    short* Ps = U + 16384;    // 2 x 1024
    const int qt = blockIdx.x;
    const int h  = blockIdx.y;
    const int tid = threadIdx.x;
    const int w  = tid >> 6;
    const int l  = tid & 63;
    const int fr = l & 15;
    const int kc = l >> 4;

    const int qrow = qt * 32 + w * 16 + fr;
    short8 qf[2];
    qf[0] = *(const short8*)(QKVb + (long)qrow * 1536 + h * 64 + kc * 8);
    qf[1] = *(const short8*)(QKVb + (long)qrow * 1536 + h * 64 + 32 + kc * 8);

    auto FILL = [&](int t, int buf) {
        const int kb = t * 64;
        #pragma unroll
        for (int it = 0; it < 4; ++it) {
            const int row = it * 16 + w * 8 + (l >> 3);
            const int sl  = ((l & 7) ^ (row & 7)) * 8;
            gload16(QKVb + (long)(kb + row) * 1536 + 512 + h * 64 + sl,
                    Ks + buf * 4096 + (it * 16 + w * 8) * 64);
            gload16(VT + (long)h * 65536 + (long)row * 1024 + kb + sl,
                    Vs + buf * 4096 + (it * 16 + w * 8) * 64);
        }
    };

    float m_i[4], l_i[4];
    f32x4 acc_o[4] = {};
    #pragma unroll
    for (int i = 0; i < 4; ++i) { m_i[i] = -1e30f; l_i[i] = 0.f; }

    short* ps = Ps + w * 1024;

    FILL(0, 0); FILL(1, 1);
    for (int t = 0; t < 16; ++t) {
        waitvm(t == 15 ? 0 : 8);
        __builtin_amdgcn_sched_barrier(0);
        __builtin_amdgcn_s_barrier();

        f32x4 sacc[4] = {};
        const int cb = t & 1;
        #pragma unroll
        for (int ks = 0; ks < 2; ++ks) {
            #pragma unroll
            for (int c = 0; c < 4; ++c) {
                const int krow = c * 16 + fr;
                const short8 kf = *(const short8*)(Ks + cb * 4096 + krow * 64 + (((ks * 4 + kc) ^ (krow & 7)) * 8));
                sacc[c] = __builtin_amdgcn_mfma_f32_16x16x32_bf16(qf[ks], kf, sacc[c], 0, 0, 0);
            }
        }

        float p[4][4];
        #pragma unroll
        for (int i = 0; i < 4; ++i) {
            float tm = fmaxf(fmaxf(sacc[0][i], sacc[1][i]), fmaxf(sacc[2][i], sacc[3][i]));
            #pragma unroll
            for (int off = 8; off; off >>= 1) tm = fmaxf(tm, __shfl_xor(tm, off));
            tm *= 0.125f;
            const float mn = fmaxf(m_i[i], tm);
            const float sc = __expf(m_i[i] - mn);
            m_i[i] = mn;
            float ts = 0.f;
            #pragma unroll
            for (int c = 0; c < 4; ++c) { p[c][i] = __expf(sacc[c][i] * 0.125f - mn); ts += p[c][i]; }
            #pragma unroll
            for (int off = 8; off; off >>= 1) ts += __shfl_xor(ts, off);
            l_i[i] = l_i[i] * sc + ts;
            #pragma unroll
            for (int c = 0; c < 4; ++c) acc_o[c][i] *= sc;
        }

        #pragma unroll
        for (int c = 0; c < 4; ++c) {
            const int col = c * 16 + fr;
            #pragma unroll
            for (int i = 0; i < 4; ++i) {
                const int row = kc * 4 + i;
                ps[row * 64 + (((col >> 3) ^ (row & 7)) * 8) + (col & 7)] = (short)f2bu(p[c][i]);
            }
        }
        short8 pf[2];
        pf[0] = *(const short8*)(ps + fr * 64 + ((kc ^ (fr & 7)) * 8));
        pf[1] = *(const short8*)(ps + fr * 64 + (((4 + kc) ^ (fr & 7)) * 8));

        #pragma unroll
        for (int ks = 0; ks < 2; ++ks) {
            #pragma unroll
            for (int c = 0; c < 4; ++c) {
                const int drow = c * 16 + fr;
                const short8 vf = *(const short8*)(Vs + cb * 4096 + drow * 64 + (((ks * 4 + kc) ^ (drow & 7)) * 8));
                acc_o[c] = __builtin_amdgcn_mfma_f32_16x16x32_bf16(pf[ks], vf, acc_o[c], 0, 0, 0);
            }
        }
        __builtin_amdgcn_s_barrier();
        if (t + 2 < 16) FILL(t + 2, (t + 2) & 1);
    }

    // -------- epilogue: O (regs) @ Wo_h^T -> per-head slab --------
    short* po = Ps + w * 1024;   // reuse P region: O as A-frag layout
    #pragma unroll
    for (int c = 0; c < 4; ++c) {
        const int col = c * 16 + fr;
        #pragma unroll
        for (int i = 0; i < 4; ++i) {
            const int r = kc * 4 + i;
            po[r * 64 + (((col >> 3) ^ (r & 7)) * 8) + (col & 7)] =
                (short)f2bu(acc_o[c][i] / l_i[i]);
        }
    }
    __syncthreads();   // retire K/V reads; po visible (own-wave)

    short* Wos = U;    // reuse Ks region: 2 x 4096 (64x64 bf16 chunks)
    float* SLABh = SLABp + (long)h * 524288;
    const int orow = qt * 32 + w * 16;

    auto WSTAGE = [&](int c8, int buf) {
        const int n0c = c8 * 64;
        #pragma unroll
        for (int it = 0; it < 4; ++it) {
            const int rb  = w * 32 + it * 8;
            const int row = rb + (l >> 3);
            const int sl  = ((l & 7) ^ (row & 7)) * 8;
            gload16(wo + (long)(n0c + row) * 512 + h * 64 + sl, Wos + buf * 4096 + rb * 64);
        }
    };

    WSTAGE(0, 0);
    for (int c8 = 0; c8 < 8; ++c8) {
        if (c8) __syncthreads();
        if (c8 + 1 < 8) WSTAGE(c8 + 1, (c8 + 1) & 1);
        waitvm(c8 + 1 < 8 ? 4 : 0);
        __builtin_amdgcn_sched_barrier(0);
        __builtin_amdgcn_s_barrier();
        const int buf = c8 & 1;
        f32x4 a2[4] = {};
        #pragma unroll
        for (int ks = 0; ks < 2; ++ks) {
            const int q = ks * 4 + kc;
            const short8 af = *(const short8*)(po + fr * 64 + ((q ^ (fr & 7)) * 8));
            #pragma unroll
            for (int ct = 0; ct < 4; ++ct) {
                const int brn = ct * 16 + fr;
                const short8 bf = *(const short8*)(Wos + buf * 4096 + brn * 64 + ((q ^ (brn & 7)) * 8));
                a2[ct] = __builtin_amdgcn_mfma_f32_16x16x32_bf16(af, bf, a2[ct], 0, 0, 0);
            }
        }
        #pragma unroll
        for (int ct = 0; ct < 4; ++ct) {
            const int n = c8 * 64 + ct * 16 + fr;
            #pragma unroll
            for (int i = 0; i < 4; ++i)
                SLABh[(long)(orow + kc * 4 + i) * 512 + n] = a2[ct][i];
        }
    }
}

// -------- LayerNorm-as-merge: out = LN(x + sum_slabs + bias)*s + b -----------
template<int NSLAB>
__global__ __launch_bounds__(256)
void ln_k(const float* __restrict__ x, const float* __restrict__ slab,
          const float* __restrict__ bias,
          const float* __restrict__ s, const float* __restrict__ b,
          float* __restrict__ out, unsigned short* __restrict__ outb)
{
    const int lane = threadIdx.x & 63;
    const int row  = (blockIdx.x << 2) + (threadIdx.x >> 6);
    const float* px = x + (long)row * 512;
    float v[8];
    float sum = 0.f;
    #pragma unroll
    for (int i = 0; i < 8; ++i) {
        const int j = lane + (i << 6);
        v[i] = px[j];
        #pragma unroll
        for (int t = 0; t < NSLAB; ++t) v[i] += slab[(long)t * 524288 + (long)row * 512 + j];
        if (NSLAB > 0) v[i] += bias[j];
        sum += v[i];
    }
    #pragma unroll
    for (int off = 32; off; off >>= 1) sum += __shfl_xor(sum, off);
    const float m = sum * (1.0f / 512.0f);
    float s2 = 0.f;
    #pragma unroll
    for (int i = 0; i < 8; ++i) { const float d = v[i] - m; s2 += d * d; }
    #pragma unroll
    for (int off = 32; off; off >>= 1) s2 += __shfl_xor(s2, off);
    const float inv = rsqrtf(s2 * (1.0f / 512.0f) + 1e-5f);
    #pragma unroll
    for (int i = 0; i < 8; ++i) {
        const int j = lane + (i << 6);
        const float r = (v[i] - m) * inv * s[j] + b[j];
        out[(long)row * 512 + j] = r;
        if (outb) outb[(long)row * 512 + j] = f2bu(r);
    }
}

// -------- fused final LN + L2-normalize --------------------------------------
__global__ __launch_bounds__(256)
void lnl2_k(const float* __restrict__ x,
            const float* __restrict__ s, const float* __restrict__ b,
            float* __restrict__ out_attn, unsigned short* __restrict__ nb)
{
    const int lane = threadIdx.x & 63;
    const int row  = (blockIdx.x << 2) + (threadIdx.x >> 6);
    const float* px = x + (long)row * 512;
    float v[8];
    float sum = 0.f;
    #pragma unroll
    for (int i = 0; i < 8; ++i) { v[i] = px[lane + (i << 6)]; sum += v[i]; }
    #pragma unroll
    for (int off = 32; off; off >>= 1) sum += __shfl_xor(sum, off);
    const float m = sum * (1.0f / 512.0f);
    float s2 = 0.f;
    #pragma unroll
    for (int i = 0; i < 8; ++i) { const float d = v[i] - m; s2 += d * d; }
    #pragma unroll
    for (int off = 32; off; off >>= 1) s2 += __shfl_xor(s2, off);
    const float inv = rsqrtf(s2 * (1.0f / 512.0f) + 1e-5f);
    float nrm = 0.f;
    #pragma unroll
    for (int i = 0; i < 8; ++i) {
        const int j = lane + (i << 6);
        v[i] = (v[i] - m) * inv * s[j] + b[j];
        out_attn[(long)row * 512 + j] = v[i];
        nrm += v[i] * v[i];
    }
    #pragma unroll
    for (int off = 32; off; off >>= 1) nrm += __shfl_xor(nrm, off);
    const float rinv = rsqrtf(nrm);
    #pragma unroll
    for (int i = 0; i < 8; ++i)
        nb[(long)row * 512 + lane + (i << 6)] = f2bu(v[i] * rinv);
}

// -------- init: x -> MEMf, Yf (fp32) + MEMb, Yb (bf16) -----------------------
__global__ __launch_bounds__(256)
void init_k(const float* __restrict__ x, float* __restrict__ mf, float* __restrict__ yf,
            unsigned short* __restrict__ mb, unsigned short* __restrict__ yb)
{
    const long i = ((long)blockIdx.x * 256 + threadIdx.x) * 4;
    const float4 v = *(const float4*)(x + i);
    *(float4*)(mf + i) = v;
    *(float4*)(yf + i) = v;
    short4v s;
    s[0] = (short)f2bu(v.x); s[1] = (short)f2bu(v.y);
    s[2] = (short)f2bu(v.z); s[3] = (short)f2bu(v.w);
    *(short4v*)(mb + i) = s;
    *(short4v*)(yb + i) = s;
}

// ------------------------------ host side ------------------------------------
static void gemm3(hipStream_t st, bool relu, bool obf16,
                  const unsigned short* A, int lda,
                  const unsigned short* B, int ldb,
                  const float* bias, void* C, int ldc, long sC,
                  int M, int N, int K, float alpha, int batch,
                  unsigned short* VTp = nullptr, int vt_col0 = 0,
                  const unsigned short* A2 = nullptr, int a2_col = 0,
                  int kz = 0)
{
    dim3 g(N / 64, M / 64, batch);
    if (obf16) {
        if (relu) gemm3_k<true,  true ><<<g, 256, 0, st>>>(A, A2, a2_col, lda, B, ldb, bias, C, ldc, sC, K, alpha, VTp, vt_col0, kz);
        else      gemm3_k<false, true ><<<g, 256, 0, st>>>(A, A2, a2_col, lda, B, ldb, bias, C, ldc, sC, K, alpha, VTp, vt_col0, kz);
    } else {
        if (relu) gemm3_k<true,  false><<<g, 256, 0, st>>>(A, A2, a2_col, lda, B, ldb, bias, C, ldc, sC, K, alpha, VTp, vt_col0, kz);
        else      gemm3_k<false, false><<<g, 256, 0, st>>>(A, A2, a2_col, lda, B, ldb, bias, C, ldc, sC, K, alpha, VTp, vt_col0, kz);
    }
}

extern "C" void kernel_launch(void* const* d_in, const int* in_sizes, int n_in,
                              void* d_out, int out_size, void* d_ws, size_t ws_size,
                              hipStream_t stream)
{
    const float* x            = (const float*)d_in[0];
    const float* enc_qkv_w    = (const float*)d_in[1];
    const float* enc_qkv_b    = (const float*)d_in[2];
    const float* enc_out_w    = (const float*)d_in[3];
    const float* enc_out_b    = (const float*)d_in[4];
    const float* enc_ff1_w    = (const float*)d_in[5];
    const float* enc_ff1_b    = (const float*)d_in[6];
    const float* enc_ff2_w    = (const float*)d_in[7];
    const float* enc_ff2_b    = (const float*)d_in[8];
    const float* enc_ln1_s    = (const float*)d_in[9];
    const float* enc_ln1_b    = (const float*)d_in[10];
    const float* enc_ln2_s    = (const float*)d_in[11];
    const float* enc_ln2_b    = (const float*)d_in[12];
    const float* dec_sa_qkv_w = (const float*)d_in[13];
    const float* dec_sa_qkv_b = (const float*)d_in[14];
    const float* dec_sa_out_w = (const float*)d_in[15];
    const float* dec_sa_out_b = (const float*)d_in[16];
    const float* dec_ca_qkv_w = (const float*)d_in[17];
    const float* dec_ca_qkv_b = (const float*)d_in[18];
    const float* dec_ca_out_w = (const float*)d_in[19];
    const float* dec_ca_out_b = (const float*)d_in[20];
    const float* dec_ff1_w    = (const float*)d_in[21];
    const float* dec_ff1_b    = (const float*)d_in[22];
    const float* dec_ff2_w    = (const float*)d_in[23];
    const float* dec_ff2_b    = (const float*)d_in[24];
    const float* dec_ln1_s    = (const float*)d_in[25];
    const float* dec_ln1_b    = (const float*)d_in[26];
    const float* dec_ln2_s    = (const float*)d_in[27];
    const float* dec_ln2_b    = (const float*)d_in[28];
    const float* dec_ln3_s    = (const float*)d_in[29];
    const float* dec_ln3_b    = (const float*)d_in[30];
    const float* enc_norm_s   = (const float*)d_in[31];
    const float* enc_norm_b   = (const float*)d_in[32];
    const float* dec_norm_s   = (const float*)d_in[33];
    const float* dec_norm_b   = (const float*)d_in[34];

    char* p = (char*)d_ws;
    auto alloc = [&](size_t bytes) -> char* {
        char* r = p; p += (bytes + 255) & ~(size_t)255; return r;
    };
    float*          MEMf = (float*)alloc(1024 * 512 * 4);
    float*          Yf   = (float*)alloc(1024 * 512 * 4);
    unsigned short* MEMb = (unsigned short*)alloc(1024 * 512 * 2);
    unsigned short* Yb   = (unsigned short*)alloc(1024 * 512 * 2);
    unsigned short* QKVb = (unsigned short*)alloc(1024 * 1536 * 2);
    unsigned short* VT   = (unsigned short*)alloc(8L * 64 * 1024 * 2);
    float*          SLAB = (float*)alloc(8L * 1024 * 512 * 4);   // 8 fp32 slabs
    unsigned short* F1b  = (unsigned short*)alloc(1024L * 2048 * 2);
    unsigned short* NBb  = (unsigned short*)alloc(1024 * 512 * 2);

    const float* wsrc[10] = {enc_qkv_w, enc_out_w, enc_ff1_w, enc_ff2_w,
                             dec_sa_qkv_w, dec_sa_out_w, dec_ca_qkv_w, dec_ca_out_w,
                             dec_ff1_w, dec_ff2_w};
    const long wper[10] = {1536L*512, 512L*512, 2048L*512, 512L*2048,
                           1536L*512, 512L*512, 1536L*512, 512L*512,
                           2048L*512, 512L*2048};
    long wtot = 0;
    for (int t = 0; t < 10; ++t) wtot += wper[t] * NLAY;

    const size_t used = (size_t)(p - (char*)d_ws);
    const bool preconv = (ws_size > used) && ((ws_size - used) >= (size_t)wtot * 2 + 4096);

    unsigned short* wpre[10] = {};
    unsigned short* slots[2] = {};
    int slot_ctr = 0;
    if (preconv) {
        WCvt wc;
        wc.cum[0] = 0;
        for (int t = 0; t < 10; ++t) {
            wpre[t] = (unsigned short*)alloc((size_t)wper[t] * NLAY * 2);
            wc.src[t] = wsrc[t];
            wc.dst[t] = wpre[t];
            wc.cum[t + 1] = wc.cum[t] + wper[t] * NLAY / 8;
        }
        f2ball_k<<<dim3(2048), 256, 0, stream>>>(wc);
    } else {
        slots[0] = (unsigned short*)alloc(2048L * 512 * 2);
        slots[1] = (unsigned short*)alloc(2048L * 512 * 2);
    }
    auto W = [&](int t, int layer) -> const unsigned short* {
        if (preconv) return wpre[t] + (long)layer * wper[t];
        unsigned short* dst = slots[(slot_ctr++) & 1];
        const long n = wper[t];
        long blocks = (n / 8 + 255) / 256; if (blocks > 2048) blocks = 2048;
        f2b_k<<<dim3((unsigned)blocks), 256, 0, stream>>>(wsrc[t] + (long)layer * wper[t], dst, n);
        return dst;
    };

    float* out_gram = (float*)d_out;
    float* out_attn = out_gram + 1024 * 1024;

    // attention block: merged QKV GEMM -> fused attn+proj (per-head slabs) -> LN<8>
    auto run_attn = [&](const unsigned short* qb, const unsigned short* kvb,
                        int wt_qkv, int wt_o, int layer, const float* bqkv,
                        const float* obias, const float* lns, const float* lnb,
                        float* xf, unsigned short* xb) {
        gemm3(stream, false, true, qb, 512, W(wt_qkv, layer), 512, bqkv,
              QKVb, 1536, 0, 1024, 1536, 512, 1.0f, 1, VT, 1024,
              (qb == kvb) ? nullptr : kvb, 512);
        attnp_k<<<dim3(32, 8), 128, 0, stream>>>(QKVb, VT, W(wt_o, layer), SLAB);
        ln_k<8><<<256, 256, 0, stream>>>(xf, SLAB, obias, lns, lnb, xf, xb);
    };
    // FFN: FF1 (relu, bf16) -> FF2 split-K(4) slabs -> LN<4>
    auto run_ffn = [&](unsigned short* inb, int wt1, int wt2, int layer,
                       const float* b1, const float* f2bias,
                       const float* lns, const float* lnb,
                       float* xf, unsigned short* xb) {
        gemm3(stream, true, true, inb, 512, W(wt1, layer), 512, b1,
              F1b, 2048, 0, 1024, 2048, 512, 1.0f, 1);
        gemm3(stream, false, false, F1b, 2048, W(wt2, layer), 2048, nullptr,
              SLAB, 512, 524288, 1024, 512, 512, 1.0f, 4, nullptr, 0, nullptr, 0, 512);
        ln_k<4><<<256, 256, 0, stream>>>(xf, SLAB, f2bias, lns, lnb, xf, xb);
    };

    init_k<<<512, 256, 0, stream>>>(x, MEMf, Yf, MEMb, Yb);

    // ----------------------------- encoder -----------------------------------
    for (int i = 0; i < NLAY; ++i) {
        run_attn(MEMb, MEMb, 0, 1, i, enc_qkv_b + i * 1536,
                 enc_out_b + i * 512, enc_ln1_s + i * 512, enc_ln1_b + i * 512, MEMf, MEMb);
        run_ffn(MEMb, 2, 3, i, enc_ff1_b + i * 2048, enc_ff2_b + i * 512,
                enc_ln2_s + i * 512, enc_ln2_b + i * 512, MEMf, MEMb);
    }
    ln_k<0><<<256, 256, 0, stream>>>(MEMf, nullptr, nullptr, enc_norm_s, enc_norm_b, MEMf, MEMb);

    // ----------------------------- decoder -----------------------------------
    for (int i = 0; i < NLAY; ++i) {
        run_attn(Yb, Yb, 4, 5, i, dec_sa_qkv_b + i * 1536,
                 dec_sa_out_b + i * 512, dec_ln1_s + i * 512, dec_ln1_b + i * 512, Yf, Yb);
        run_attn(Yb, MEMb, 6, 7, i, dec_ca_qkv_b + i * 1536,
                 dec_ca_out_b + i * 512, dec_ln2_s + i * 512, dec_ln2_b + i * 512, Yf, Yb);
        run_ffn(Yb, 8, 9, i, dec_ff1_b + i * 2048, dec_ff2_b + i * 512,
                dec_ln3_s + i * 512, dec_ln3_b + i * 512, Yf, Yb);
    }

    // final: attention_out + n = rownorm (fused), gram = n@n^T
    lnl2_k<<<256, 256, 0, stream>>>(Yf, dec_norm_s, dec_norm_b, out_attn, NBb);
    gemm3(stream, false, false, NBb, 512, NBb, 512, nullptr,
          out_gram, 1024, 0, 1024, 1024, 512, 1.0f, 1);
}